// Round 7
// baseline (7051.307 us; speedup 1.0000x reference)
//
#include <hip/hip_runtime.h>
#include <cstdint>
#include <cmath>

#define NN   4096
#define EE   5
#define WIN  512
#define WOUT 128
#define HH0  1152   // WIN + EE*WOUT
#define NLAY 64
#define NCLS 16
#define MT   1024
#define GCAP 96     // per-(e,node) list cap; Binomial(4096,0.01) max ~70
#define BCAP 320    // per-node union cap; Binomial(4096,0.049) max ~260
#define ECAP 48     // per-(e, quarter-row) cap
#define KSPLIT 8
#define KCHUNK 512  // KSPLIT*KCHUNK == NN
#define NTILE  8    // KCHUNK / 64

typedef __attribute__((ext_vector_type(8))) short     bf16x8_t;
typedef __attribute__((ext_vector_type(8))) unsigned short ushort8_t;
typedef __attribute__((ext_vector_type(4))) float     f32x4_t;

__device__ inline unsigned short f2bf(float f) {
  unsigned int u = __float_as_uint(f);
  unsigned int r = (u + 0x7FFFu + ((u >> 16) & 1u)) >> 16;  // RNE
  return (unsigned short)r;
}

// async global->LDS, 16B per lane: dest = lds_base(wave-uniform) + lane*16
__device__ __forceinline__ void gload16(const unsigned short* g, unsigned short* l) {
  __builtin_amdgcn_global_load_lds(
      (__attribute__((address_space(1))) void*)g,
      (__attribute__((address_space(3))) void*)l, 16, 0, 0);
}

// ---------------------------------------------------------------------------
// Generic register-tiled fp32 GEMM: C = act(A[M,K] @ W[K,N] + bias)
// 64x64 tile, 256 threads, 4x4 outputs/thread, BK=16. act:0=none,1=relu,2=leaky
// ---------------------------------------------------------------------------
__global__ __launch_bounds__(256) void gemm_kernel(
    const float* __restrict__ A, const float* __restrict__ W,
    const float* __restrict__ bias, float* __restrict__ C,
    int Mdim, int Kdim, int Ndim, int act) {
  __shared__ __align__(16) float sA[16][68];
  __shared__ __align__(16) float sW[16][64];
  int tid = threadIdx.x;
  int tx = tid & 15, ty = tid >> 4;
  int row0 = blockIdx.y * 64, col0 = blockIdx.x * 64;
  float acc[4][4] = {};
  int mA = tid >> 2;
  int kA = (tid & 3) << 2;
  int kW = tid >> 4;
  int nW = (tid & 15) << 2;
  for (int k0 = 0; k0 < Kdim; k0 += 16) {
    float4 av = *(const float4*)(A + (size_t)(row0 + mA) * Kdim + k0 + kA);
    float4 wv = *(const float4*)(W + (size_t)(k0 + kW) * Ndim + col0 + nW);
    sA[kA + 0][mA] = av.x;
    sA[kA + 1][mA] = av.y;
    sA[kA + 2][mA] = av.z;
    sA[kA + 3][mA] = av.w;
    *(float4*)&sW[kW][nW] = wv;
    __syncthreads();
#pragma unroll
    for (int kk = 0; kk < 16; kk++) {
      float4 a = *(const float4*)&sA[kk][ty << 2];
      float4 b = *(const float4*)&sW[kk][tx << 2];
      acc[0][0] += a.x * b.x; acc[0][1] += a.x * b.y; acc[0][2] += a.x * b.z; acc[0][3] += a.x * b.w;
      acc[1][0] += a.y * b.x; acc[1][1] += a.y * b.y; acc[1][2] += a.y * b.z; acc[1][3] += a.y * b.w;
      acc[2][0] += a.z * b.x; acc[2][1] += a.z * b.y; acc[2][2] += a.z * b.z; acc[2][3] += a.z * b.w;
      acc[3][0] += a.w * b.x; acc[3][1] += a.w * b.y; acc[3][2] += a.w * b.z; acc[3][3] += a.w * b.w;
    }
    __syncthreads();
  }
#pragma unroll
  for (int i = 0; i < 4; i++) {
    int r = row0 + (ty << 2) + i;
#pragma unroll
    for (int jc = 0; jc < 4; jc++) {
      int c = col0 + (tx << 2) + jc;
      float o = acc[i][jc];
      if (bias) o += bias[c];
      if (act == 1) o = fmaxf(o, 0.f);
      else if (act == 2) o = (o >= 0.f) ? o : 0.01f * o;
      C[(size_t)r * Ndim + c] = o;
    }
  }
}

// ---------------------------------------------------------------------------
// Forward scan: block = quarter-row, coalesced list build.
// ---------------------------------------------------------------------------
__global__ __launch_bounds__(256) void scan_rows_kernel(
    const float* __restrict__ A, int* __restrict__ fcnt, int* __restrict__ fidx,
    float* __restrict__ fval, int* __restrict__ bcnt, int* __restrict__ bidx) {
  __shared__ int   lbuf[1024];
  __shared__ int   lcnt;
  __shared__ int   ecnt[EE];
  __shared__ int   en2[EE][ECAP];
  __shared__ float ev[EE][ECAP];
  __shared__ int   rbase;
  __shared__ int   gbase[EE];
  int tid = threadIdx.x;
  int n1 = blockIdx.x >> 2;
  int qb = (blockIdx.x & 3) << 10;
  if (tid == 0) lcnt = 0;
  if (tid < EE) ecnt[tid] = 0;
  __syncthreads();
  const float4* src = (const float4*)(A + ((size_t)n1 * NN + qb) * EE);
  float buf[20];
  float4* bf4 = (float4*)buf;
#pragma unroll
  for (int c = 0; c < 5; c++) bf4[c] = src[tid * 5 + c];
  int n2base = qb + tid * 4;
#pragma unroll
  for (int u = 0; u < 4; u++) {
    int n2 = n2base + u;
    if (n2 == n1) continue;
    bool any = false;
#pragma unroll
    for (int e = 0; e < EE; e++) {
      float v = buf[u * 5 + e];
      if (v != 0.f) {
        any = true;
        int s = atomicAdd(&ecnt[e], 1);
        if (s < ECAP) { en2[e][s] = n2; ev[e][s] = v; }
      }
    }
    if (any) {
      int s = atomicAdd(&lcnt, 1);
      lbuf[s] = n2;
    }
  }
  __syncthreads();
  if (tid == 0) rbase = atomicAdd(&bcnt[n1], lcnt);
  if (tid < EE) gbase[tid] = atomicAdd(&fcnt[tid * NN + n1], min(ecnt[tid], ECAP));
  __syncthreads();
  int c = lcnt, rb = rbase;
  for (int s = tid; s < c; s += 256)
    if (rb + s < BCAP) bidx[(size_t)n1 * BCAP + rb + s] = lbuf[s];
#pragma unroll
  for (int e = 0; e < EE; e++) {
    int ec = min(ecnt[e], ECAP), gb = gbase[e];
    size_t base = ((size_t)e * NN + n1) * GCAP;
    for (int s = tid; s < ec; s += 256) {
      if (gb + s < GCAP) {
        fidx[base + gb + s] = en2[e][s];
        fval[base + gb + s] = ev[e][s];
      }
    }
  }
}

// Forward -> transposed gcn lists (for lgcn).
__global__ __launch_bounds__(64) void transpose_kernel(
    const int* __restrict__ fcnt, const int* __restrict__ fidx, const float* __restrict__ fval,
    int* __restrict__ gcnt, int* __restrict__ gidx, float* __restrict__ gval) {
  int id = blockIdx.x;                      // e*NN + n1
  int n1 = id & (NN - 1);
  int e  = id >> 12;
  int c = min(fcnt[id], GCAP);
  for (int s = threadIdx.x; s < c; s += 64) {
    int   n2 = fidx[(size_t)id * GCAP + s];
    float v  = fval[(size_t)id * GCAP + s];
    int t = e * NN + n2;
    int slot = atomicAdd(&gcnt[t], 1);
    if (slot < GCAP) {
      gidx[(size_t)t * GCAP + slot] = n1;
      gval[(size_t)t * GCAP + slot] = v;
    }
  }
}

// dinv[e,i] = 1/(1 + sum gval)   ;   dis[i] = rsqrt(1 + bcnt[i])
__global__ void dinv_dis_kernel(const int* __restrict__ gcnt, const float* __restrict__ gval,
                                float* __restrict__ dinv, const int* __restrict__ bcnt,
                                float* __restrict__ dis) {
  int t = blockIdx.x * 256 + threadIdx.x;
  if (t < EE * NN) {
    int cnt = min(gcnt[t], GCAP);
    float s = 1.0f;
    for (int k = 0; k < cnt; k++) s += gval[(size_t)t * GCAP + k];
    dinv[t] = 1.0f / s;
  }
  if (t < NN) dis[t] = rsqrtf(1.0f + (float)min(bcnt[t], BCAP));
}

// ---------------------------------------------------------------------------
// Dense A_hat bf16 build: one block per row i; bitmap of neighbors in LDS,
// coalesced 8 KB row write. Ab[i][j] = (B[i][j]||i==j) ? dis[i]*dis[j] : 0.
// ---------------------------------------------------------------------------
__global__ __launch_bounds__(256) void build_ahat_kernel(
    const int* __restrict__ bcnt, const int* __restrict__ bidx,
    const float* __restrict__ dis, unsigned short* __restrict__ Ab) {
  __shared__ unsigned int bits[128];
  int i = blockIdx.x, t = threadIdx.x;
  if (t < 128) bits[t] = 0;
  __syncthreads();
  int cnt = min(bcnt[i], BCAP);
  for (int s = t; s < cnt; s += 256) {
    int j = bidx[(size_t)i * BCAP + s];
    atomicOr(&bits[j >> 5], 1u << (j & 31));
  }
  __syncthreads();
  float di = dis[i];
  int c0 = t * 16;
  unsigned short out[16];
#pragma unroll
  for (int u = 0; u < 16; u++) {
    int j = c0 + u;
    bool on = ((bits[j >> 5] >> (j & 31)) & 1u) || (j == i);
    out[u] = on ? f2bf(di * dis[j]) : (unsigned short)0;
  }
  *(ushort8_t*)&Ab[(size_t)i * NN + c0]     = *(ushort8_t*)&out[0];
  *(ushort8_t*)&Ab[(size_t)i * NN + c0 + 8] = *(ushort8_t*)&out[8];
}

// lgcn[e,i,d] = relu( dinv[e,i] * (Xw[i,d] + sum_s v_s * Xw[j_s,d]) )
__global__ __launch_bounds__(128) void lgcn_kernel(
    const int* __restrict__ gcnt, const int* __restrict__ gidx, const float* __restrict__ gval,
    const float* __restrict__ dinv, const float* __restrict__ Xw, float* __restrict__ lgcn) {
  int i = blockIdx.x, e = blockIdx.y, d = threadIdx.x;
  int t = e * NN + i;
  int cnt = min(gcnt[t], GCAP);
  __shared__ int   sj[GCAP];
  __shared__ float sv[GCAP];
  for (int s = d; s < cnt; s += 128) {
    sj[s] = gidx[(size_t)t * GCAP + s];
    sv[s] = gval[(size_t)t * GCAP + s];
  }
  __syncthreads();
  float acc = Xw[(size_t)i * WOUT + d];
  for (int s = 0; s < cnt; s++) acc += sv[s] * Xw[(size_t)sj[s] * WOUT + d];
  float r = dinv[t] * acc;
  lgcn[(size_t)t * WOUT + d] = fmaxf(r, 0.f);
}

__global__ void att_partial_kernel(const float* __restrict__ lgcn, const float* __restrict__ attw,
                                   float* __restrict__ tm_pre) {
  int e = blockIdx.y, d = threadIdx.x;
  int nbase = blockIdx.x * 128;
  float acc = 0.f;
  for (int k = 0; k < 128; k++) {
    int n = nbase + k;
    acc += attw[n] * lgcn[((size_t)(e * NN + n)) * WOUT + d];
  }
  atomicAdd(&tm_pre[e * WOUT + d], acc);
}

__global__ void att_final_kernel(const float* __restrict__ tm_pre, const float* __restrict__ attb,
                                 const float* __restrict__ attq, float* __restrict__ beta) {
  int lane = threadIdx.x;  // 64
  __shared__ float sw[EE];
  for (int e = 0; e < EE; e++) {
    float v = 0.f;
    for (int d = lane; d < WOUT; d += 64) {
      float tmv = tanhf(tm_pre[e * WOUT + d] + attb[d]);
      v += tmv * attq[d];
    }
    for (int off = 32; off; off >>= 1) v += __shfl_down(v, off, 64);
    if (lane == 0) sw[e] = v;
  }
  __syncthreads();
  if (lane == 0) {
    float mx = sw[0];
    for (int e = 1; e < EE; e++) mx = fmaxf(mx, sw[e]);
    float se = 0.f, ex[EE];
    for (int e = 0; e < EE; e++) { ex[e] = expf(sw[e] - mx); se += ex[e]; }
    for (int e = 0; e < EE; e++) beta[e] = ex[e] / se * (float)EE;
  }
}

__global__ void xcat_kernel(const float* __restrict__ lgcn, const float* __restrict__ X,
                            const float* __restrict__ beta, float* __restrict__ Xc) {
  int idx = blockIdx.x * 256 + threadIdx.x;
  const int total = NN * HH0;
  for (; idx < total; idx += gridDim.x * 256) {
    int n = idx / HH0, c = idx - n * HH0;
    float v;
    if (c < EE * WOUT) {
      int e = c >> 7, d = c & 127;
      v = beta[e] * lgcn[((size_t)(e * NN + n)) * WOUT + d];
    } else {
      v = X[(size_t)n * WIN + (c - EE * WOUT)];
    }
    Xc[idx] = v;
  }
}

// ---------------------------------------------------------------------------
// x (fp32 [NN][128]) -> xT (bf16 [128][NN]) via LDS transpose. 32 rows/block.
// ---------------------------------------------------------------------------
__global__ __launch_bounds__(256) void xT_convert_kernel(
    const float* __restrict__ x, unsigned short* __restrict__ xT) {
  __shared__ float sh2[128][36];    // [c][r]
  int r0 = blockIdx.x * 32, t = threadIdx.x;
  const float4* x4 = (const float4*)(x + (size_t)r0 * WOUT);
#pragma unroll
  for (int q = 0; q < 4; q++) {
    int lin = t + q * 256;          // float4 index in 32x128 tile
    int r = lin >> 5, c = (lin & 31) * 4;
    float4 v = x4[lin];
    sh2[c + 0][r] = v.x; sh2[c + 1][r] = v.y; sh2[c + 2][r] = v.z; sh2[c + 3][r] = v.w;
  }
  __syncthreads();
  int c = t >> 1, half = t & 1;
  unsigned short tmp[16];
#pragma unroll
  for (int rr = 0; rr < 16; rr++) tmp[rr] = f2bf(sh2[c][half * 16 + rr]);
  *(ushort8_t*)&xT[(size_t)c * NN + r0 + half * 16]     = *(ushort8_t*)&tmp[0];
  *(ushort8_t*)&xT[(size_t)c * NN + r0 + half * 16 + 8] = *(ushort8_t*)&tmp[8];
}

// ---------------------------------------------------------------------------
// Fused SpMM + split-K semaphore epilogue.
// SpMM part = R3-verified: 64 rows x 128 cols/block, K-chunk 512 (KSPLIT 8),
// grid 512 (2/CU). Double-buffered BK=64 stages (two BK=32 sub-tiles, 64B
// rows -> conflict-free ds_read_b128), global_load_lds w16, 6 chunk
// descriptors/wave. After the P write each block release-fences and bumps
// cnt[rt]; the LAST arriver (8th) acquire-fences and runs the GCNII
// epilogue for its 64 rows (4 x 16-row groups, fp32, bit-identical to the
// old gcnii_epi_kernel). Saves 64 launches/drains per iteration and keeps
// the P round-trip on-die (wbL2 -> L3 -> inv -> read).
// Layouts (m89/m91-verified): A-frag A[m=lane&15][k=quad*8+j];
// B-frag B[k=quad*8+j][n=lane&15]; C/D col=lane&15,row=quad*4+reg.
// ---------------------------------------------------------------------------
#define SUBSZ (128 * 32)   // one BK=32 sub-tile (shorts)
__global__ __launch_bounds__(256) void spmm_epi_kernel(
    const unsigned short* __restrict__ Ab, const unsigned short* __restrict__ xbT,
    float* __restrict__ P, int* __restrict__ cnt,
    const float* __restrict__ x0, const float* __restrict__ Wl, float bl,
    float* __restrict__ xout_f32, unsigned short* __restrict__ xoutT, int write_f32) {
  __shared__ __align__(16) unsigned short sT[2][12288];
  __shared__ float sh2[128][22];   // epi transpose buffer (reused per group)
  __shared__ int slast;
  int t = threadIdx.x;
  int rt = blockIdx.x & 63, kc = blockIdx.x >> 6;
  int r0 = rt * 64, k0 = kc * KCHUNK;
  int wave = t >> 6, lane = t & 63;
  int wr = (wave & 1) * 32, wc = (wave >> 1) * 64;
  int quad = lane >> 4, mrow = lane & 15;
  f32x4_t acc[2][4] = {};

  // 6 staging chunks per wave; chunk = 16 rows x 64B. c<8: A, else X.
  const unsigned short* gq[6];
  int lq[6];
#pragma unroll
  for (int q = 0; q < 6; q++) {
    int c = wave * 6 + q;
    if (c < 8) {
      int sub = c >> 2, rb = c & 3;
      gq[q] = Ab + (size_t)(r0 + rb * 16 + (lane >> 2)) * NN + k0 + sub * 32 + (lane & 3) * 8;
      lq[q] = sub * 2048 + rb * 512;
    } else {
      int cc = c - 8;
      int sub = cc >> 3, rb = cc & 7;
      gq[q] = xbT + (size_t)(rb * 16 + (lane >> 2)) * NN + k0 + sub * 32 + (lane & 3) * 8;
      lq[q] = 4096 + sub * 4096 + rb * 512;
    }
  }

#define STAGE(BUF, TS)                                         \
  {                                                            \
    unsigned short* lb = &sT[(BUF)][0];                        \
    _Pragma("unroll")                                          \
    for (int q = 0; q < 6; q++)                                \
      gload16(gq[q] + (TS) * 64, lb + lq[q]);                  \
  }

  STAGE(0, 0);
  asm volatile("s_waitcnt vmcnt(0)" ::: "memory");
  __builtin_amdgcn_s_barrier();

  int cur = 0;
  for (int tt = 0; tt < NTILE; tt++) {
    if (tt < NTILE - 1) STAGE(cur ^ 1, tt + 1);
    const unsigned short* base = &sT[cur][0];
    bf16x8_t af[2][2], bfv[2][4];
#pragma unroll
    for (int kk = 0; kk < 2; kk++) {
#pragma unroll
      for (int mi = 0; mi < 2; mi++)
        af[kk][mi] = *(const bf16x8_t*)&base[kk * 2048 + (wr + mi * 16 + mrow) * 32 + quad * 8];
#pragma unroll
      for (int nj = 0; nj < 4; nj++)
        bfv[kk][nj] = *(const bf16x8_t*)&base[4096 + kk * 4096 + (wc + nj * 16 + mrow) * 32 + quad * 8];
    }
#pragma unroll
    for (int kk = 0; kk < 2; kk++)
#pragma unroll
      for (int mi = 0; mi < 2; mi++)
#pragma unroll
        for (int nj = 0; nj < 4; nj++)
          acc[mi][nj] = __builtin_amdgcn_mfma_f32_16x16x32_bf16(af[kk][mi], bfv[kk][nj], acc[mi][nj], 0, 0, 0);
    if (tt < NTILE - 1) {
      asm volatile("s_waitcnt vmcnt(0)" ::: "memory");  // next-tile loads landed
      __builtin_amdgcn_s_barrier();                      // reads done, writes visible
      cur ^= 1;
    }
  }
#undef STAGE

  float* Pk = P + (size_t)kc * (NN * WOUT);
#pragma unroll
  for (int mi = 0; mi < 2; mi++)
#pragma unroll
    for (int nj = 0; nj < 4; nj++) {
#pragma unroll
      for (int r4 = 0; r4 < 4; r4++) {
        int row = r0 + wr + mi * 16 + quad * 4 + r4;
        int col = wc + nj * 16 + mrow;
        Pk[(size_t)row * WOUT + col] = acc[mi][nj][r4];
      }
    }

  // ---- split-K semaphore: last arriver for this row-tile runs the epi ----
  __threadfence();                 // release: flush P writes (wbL2)
  __syncthreads();                 // all threads' stores fenced
  if (t == 0) slast = (atomicAdd(&cnt[rt], 1) == KSPLIT - 1) ? 1 : 0;
  __syncthreads();
  if (!slast) return;
  __threadfence();                 // acquire: invalidate stale L2 lines

  float c1 = 1.f - bl;
#pragma unroll 1
  for (int g = 0; g < 4; g++) {
    int e0 = r0 + g * 16;
    // 1) reduce partials + residual -> sh2 (transposed store)
#pragma unroll
    for (int q = 0; q < 2; q++) {
      int lin = t + q * 256;       // float4 index in 16x128 tile
      int r = lin >> 5, cl = (lin & 31) * 4;
      size_t base4 = ((size_t)(e0 + r) * WOUT + cl) >> 2;
      float4 s = {0.f, 0.f, 0.f, 0.f};
#pragma unroll
      for (int k2 = 0; k2 < KSPLIT; k2++) {
        float4 p = ((const float4*)P)[(size_t)k2 * (NN * WOUT / 4) + base4];
        s.x += p.x; s.y += p.y; s.z += p.z; s.w += p.w;
      }
      float4 xv = ((const float4*)x0)[base4];
      s.x = 0.9f * s.x + 0.1f * xv.x;
      s.y = 0.9f * s.y + 0.1f * xv.y;
      s.z = 0.9f * s.z + 0.1f * xv.z;
      s.w = 0.9f * s.w + 0.1f * xv.w;
      sh2[cl + 0][r] = s.x; sh2[cl + 1][r] = s.y; sh2[cl + 2][r] = s.z; sh2[cl + 3][r] = s.w;
    }
    __syncthreads();
    // 2) dense h@Wl, register-tiled 2x4 (rows ty2*2.., cols tx2*4..)
    int tx2 = t & 31, ty2 = t >> 5;
    float2 hv[4];
#pragma unroll
    for (int j = 0; j < 4; j++) hv[j] = *(const float2*)&sh2[tx2 * 4 + j][ty2 * 2];
    float o[2][4] = {};
    for (int k = 0; k < WOUT; k++) {
      float2 a = *(const float2*)&sh2[k][ty2 * 2];
      float4 w = *(const float4*)&Wl[k * WOUT + tx2 * 4];
      o[0][0] += a.x * w.x; o[0][1] += a.x * w.y; o[0][2] += a.x * w.z; o[0][3] += a.x * w.w;
      o[1][0] += a.y * w.x; o[1][1] += a.y * w.y; o[1][2] += a.y * w.z; o[1][3] += a.y * w.w;
    }
    float y[2][4];
    float hvv[2][4] = {{hv[0].x, hv[1].x, hv[2].x, hv[3].x},
                       {hv[0].y, hv[1].y, hv[2].y, hv[3].y}};
#pragma unroll
    for (int i = 0; i < 2; i++)
#pragma unroll
      for (int j = 0; j < 4; j++)
        y[i][j] = fmaxf(c1 * hvv[i][j] + bl * o[i][j], 0.f);
    if (write_f32) {
#pragma unroll
      for (int i = 0; i < 2; i++) {
        float4 v = {y[i][0], y[i][1], y[i][2], y[i][3]};
        *(float4*)&xout_f32[(size_t)(e0 + ty2 * 2 + i) * WOUT + tx2 * 4] = v;
      }
    }
    __syncthreads();   // done reading sh2 as h
#pragma unroll
    for (int i = 0; i < 2; i++)
#pragma unroll
      for (int j = 0; j < 4; j++)
        sh2[tx2 * 4 + j][ty2 * 2 + i] = y[i][j];
    __syncthreads();
    // 3) transposed bf16 write: col cc, 8 rows per thread
    int cc = t >> 1, half = t & 1;
    unsigned short tmp[8];
#pragma unroll
    for (int rr = 0; rr < 8; rr++) tmp[rr] = f2bf(sh2[cc][half * 8 + rr]);
    *(ushort8_t*)&xoutT[(size_t)cc * NN + e0 + half * 8] = *(ushort8_t*)&tmp[0];
    __syncthreads();   // sh2 reused next group
  }
}

// y = Z[tx]@W2 + b2 ; per-row log-softmax ; per-block loss partials
__global__ __launch_bounds__(256) void head_kernel(
    const float* __restrict__ Z, const int* __restrict__ txv, const int* __restrict__ tgt,
    const float* __restrict__ W2, const float* __restrict__ b2,
    float* __restrict__ out_y, float* __restrict__ lossp) {
  int tid = threadIdx.x;
  int mr = tid >> 4, c = tid & 15;
  int m = blockIdx.x * 16 + mr;
  const float* zr = Z + (size_t)txv[m] * WOUT;
  float acc = b2[c];
  for (int k = 0; k < WOUT; k++) acc += zr[k] * W2[k * NCLS + c];
  out_y[(size_t)m * NCLS + c] = acc;
  float mx = acc;
  for (int off = 8; off; off >>= 1) mx = fmaxf(mx, __shfl_xor(mx, off, 16));
  float ex = expf(acc - mx);
  float se = ex;
  for (int off = 8; off; off >>= 1) se += __shfl_xor(se, off, 16);
  float lse = mx + logf(se);
  float contrib = (c == tgt[m]) ? (lse - acc) : 0.f;
  __shared__ float red[256];
  red[tid] = contrib;
  __syncthreads();
  for (int stp = 128; stp; stp >>= 1) {
    if (tid < stp) red[tid] += red[tid + stp];
    __syncthreads();
  }
  if (tid == 0) lossp[blockIdx.x] = red[0];
}

__global__ void loss_final_kernel(const float* __restrict__ lossp, float* __restrict__ out_loss) {
  int lane = threadIdx.x;
  float v = (lane < 64) ? lossp[lane] : 0.f;
  for (int off = 32; off; off >>= 1) v += __shfl_down(v, off, 64);
  if (lane == 0) out_loss[0] = v / (float)MT;
}

// ---------------------------------------------------------------------------
extern "C" void kernel_launch(void* const* d_in, const int* in_sizes, int n_in,
                              void* d_out, int out_size, void* d_ws, size_t ws_size,
                              hipStream_t stream) {
  const float* A      = (const float*)d_in[0];
  const float* X      = (const float*)d_in[1];
  const int*   txv    = (const int*)d_in[2];
  const int*   tgt    = (const int*)d_in[3];
  const float* weight = (const float*)d_in[4];
  const float* attw   = (const float*)d_in[5];
  const float* attb   = (const float*)d_in[6];
  const float* attq   = (const float*)d_in[7];
  const float* Wg     = (const float*)d_in[8];
  const float* bg     = (const float*)d_in[9];
  const float* W0     = (const float*)d_in[10];
  const float* b0     = (const float*)d_in[11];
  const float* Wconvs = (const float*)d_in[12];
  const float* Wd1    = (const float*)d_in[13];
  const float* bd1    = (const float*)d_in[14];
  const float* W1     = (const float*)d_in[15];
  const float* b1     = (const float*)d_in[16];
  const float* W2     = (const float*)d_in[17];
  const float* b2     = (const float*)d_in[18];

  float* ws  = (float*)d_ws;
  int*   wsi = (int*)d_ws;

  // offsets in 4-byte units (~110 MB total; ws >= 1.3 GB per harness poison)
  const size_t O_GCNT  = 0;                         // 20480 ints
  const size_t O_BCNT  = 20480;                     // 4096
  const size_t O_FCNT  = 24576;                     // 20480
  const size_t O_DINV  = 45056;                     // 20480
  const size_t O_DIS   = 65536;                     // 4096
  const size_t O_TMPRE = 69632;                     // 640
  const size_t O_BETA  = 70272;                     // 16
  const size_t O_LOSSP = 70288;                     // 64
  const size_t O_GIDX  = 71680;                     // 1966080
  const size_t O_GVAL  = O_GIDX + 1966080;
  const size_t O_FIDX  = O_GVAL + 1966080;
  const size_t O_FVAL  = O_FIDX + 1966080;
  const size_t O_BIDX  = O_FVAL + 1966080;          // 1310720
  const size_t O_LGCN  = O_BIDX + 1310720;          // 2621440
  const size_t O_XW    = O_LGCN + 2621440;          // 524288
  const size_t O_X0    = O_XW   + 524288;           // 524288
  const size_t O_XA    = O_X0   + 524288;           // 524288
  const size_t O_XB    = O_XA   + 524288;           // 524288
  const size_t O_AB    = O_XB   + 524288;           // 8388608 (4096x4096 bf16)
  const size_t O_XBT0  = O_AB   + 8388608;          // 262144  (128x4096 bf16)
  const size_t O_XBT1  = O_XBT0 + 262144;           // 262144
  const size_t O_P     = O_XBT1 + 262144;           // 4194304 (8x4096x128 f32)
  const size_t O_CNT   = O_P    + 4194304;          // 4096 ints (NLAY x 64)
  // aliases (lifetimes verified by launch order):
  const size_t O_T1    = O_FVAL;   // [4096,512] dead before scan writes fval/bidx
  const size_t O_XCAT  = O_GIDX;   // [4096,1152] built after gidx/gval/fidx last reads

  hipMemsetAsync(ws + O_GCNT, 0, 45056 * 4, stream);   // gcnt+bcnt+fcnt
  hipMemsetAsync(ws + O_TMPRE, 0, 640 * 4, stream);
  hipMemsetAsync(ws + O_CNT, 0, 4096 * 4, stream);     // split-K semaphores

  dim3 blk(256);
  // Stage A: Xw = leaky(leaky(X@Wg+bg)@weight)
  gemm_kernel<<<dim3(WIN / 64, NN / 64), blk, 0, stream>>>(X, Wg, bg, ws + O_T1, NN, WIN, WIN, 2);
  gemm_kernel<<<dim3(WOUT / 64, NN / 64), blk, 0, stream>>>(ws + O_T1, weight, nullptr, ws + O_XW, NN, WIN, WOUT, 2);
  // Stage B: sparse structures + dense A_hat
  scan_rows_kernel<<<NN * 4, 256, 0, stream>>>(A, wsi + O_FCNT, wsi + O_FIDX, ws + O_FVAL,
                                               wsi + O_BCNT, wsi + O_BIDX);
  transpose_kernel<<<EE * NN, 64, 0, stream>>>(wsi + O_FCNT, wsi + O_FIDX, ws + O_FVAL,
                                               wsi + O_GCNT, wsi + O_GIDX, ws + O_GVAL);
  dinv_dis_kernel<<<80, 256, 0, stream>>>(wsi + O_GCNT, ws + O_GVAL, ws + O_DINV,
                                          wsi + O_BCNT, ws + O_DIS);
  build_ahat_kernel<<<NN, 256, 0, stream>>>(wsi + O_BCNT, wsi + O_BIDX, ws + O_DIS,
                                            (unsigned short*)(ws + O_AB));
  // Stage C: lgcn
  lgcn_kernel<<<dim3(NN, EE), 128, 0, stream>>>(wsi + O_GCNT, wsi + O_GIDX, ws + O_GVAL,
                                                ws + O_DINV, ws + O_XW, ws + O_LGCN);
  // Stage D: attention -> beta
  att_partial_kernel<<<dim3(32, EE), 128, 0, stream>>>(ws + O_LGCN, attw, ws + O_TMPRE);
  att_final_kernel<<<1, 64, 0, stream>>>(ws + O_TMPRE, attb, attq, ws + O_BETA);
  // Stage E: X_ and x0
  xcat_kernel<<<4096, 256, 0, stream>>>(ws + O_LGCN, X, ws + O_BETA, ws + O_XCAT);
  gemm_kernel<<<dim3(WOUT / 64, NN / 64), blk, 0, stream>>>(ws + O_XCAT, W0, b0, ws + O_X0, NN, HH0, WOUT, 1);
  xT_convert_kernel<<<NN / 32, 256, 0, stream>>>(ws + O_X0, (unsigned short*)(ws + O_XBT0));
  // Stage F: 64 GCNII layers (fused spmm + semaphore epilogue, 1 launch/layer)
  for (int l = 0; l < NLAY; l++) {
    float bl = logf(0.5f / (float)(l + 1) + 1.0f);
    const unsigned short* xin = (const unsigned short*)(ws + ((l & 1) ? O_XBT1 : O_XBT0));
    unsigned short* xoT = (unsigned short*)(ws + ((l & 1) ? O_XBT0 : O_XBT1));
    spmm_epi_kernel<<<64 * KSPLIT, 256, 0, stream>>>(
        (const unsigned short*)(ws + O_AB), xin, ws + O_P, wsi + O_CNT + l * 64,
        ws + O_X0, Wconvs + (size_t)l * WOUT * WOUT, bl,
        ws + O_XA, xoT, (l == NLAY - 1) ? 1 : 0);
  }
  // Stage G: head (fp32 x in O_XA)
  gemm_kernel<<<dim3(WOUT / 64, NN / 64), blk, 0, stream>>>(ws + O_XA, Wd1, bd1, ws + O_XB, NN, WOUT, WOUT, 2);
  gemm_kernel<<<dim3(WOUT / 64, NN / 64), blk, 0, stream>>>(ws + O_XB, W1, b1, ws + O_X0, NN, WOUT, WOUT, 2);
  head_kernel<<<MT / 16, 256, 0, stream>>>(ws + O_X0, txv, tgt, W2, b2,
                                           (float*)d_out + 1, ws + O_LOSSP);
  loss_final_kernel<<<1, 64, 0, stream>>>(ws + O_LOSSP, (float*)d_out);
}

// Round 8
// 3504.743 us; speedup vs baseline: 2.0119x; 2.0119x over previous
//
#include <hip/hip_runtime.h>
#include <cstdint>
#include <cmath>

#define NN   4096
#define EE   5
#define WIN  512
#define WOUT 128
#define HH0  1152   // WIN + EE*WOUT
#define NLAY 64
#define NCLS 16
#define MT   1024
#define GCAP 96     // per-(e,node) list cap; Binomial(4096,0.01) max ~70
#define BCAP 320    // per-node union cap; Binomial(4096,0.049) max ~260
#define ECAP 48     // per-(e, quarter-row) cap

typedef __attribute__((ext_vector_type(8))) short     bf16x8_t;
typedef __attribute__((ext_vector_type(8))) unsigned short ushort8_t;
typedef __attribute__((ext_vector_type(4))) float     f32x4_t;

__device__ inline unsigned short f2bf(float f) {
  unsigned int u = __float_as_uint(f);
  unsigned int r = (u + 0x7FFFu + ((u >> 16) & 1u)) >> 16;  // RNE
  return (unsigned short)r;
}

// async global->LDS, 16B per lane: dest = lds_base(wave-uniform) + lane*16
__device__ __forceinline__ void gload16(const unsigned short* g, unsigned short* l) {
  __builtin_amdgcn_global_load_lds(
      (__attribute__((address_space(1))) void*)g,
      (__attribute__((address_space(3))) void*)l, 16, 0, 0);
}

// ---------------------------------------------------------------------------
// Generic register-tiled fp32 GEMM: C = act(A[M,K] @ W[K,N] + bias)
// 64x64 tile, 256 threads, 4x4 outputs/thread, BK=16. act:0=none,1=relu,2=leaky
// ---------------------------------------------------------------------------
__global__ __launch_bounds__(256) void gemm_kernel(
    const float* __restrict__ A, const float* __restrict__ W,
    const float* __restrict__ bias, float* __restrict__ C,
    int Mdim, int Kdim, int Ndim, int act) {
  __shared__ __align__(16) float sA[16][68];
  __shared__ __align__(16) float sW[16][64];
  int tid = threadIdx.x;
  int tx = tid & 15, ty = tid >> 4;
  int row0 = blockIdx.y * 64, col0 = blockIdx.x * 64;
  float acc[4][4] = {};
  int mA = tid >> 2;
  int kA = (tid & 3) << 2;
  int kW = tid >> 4;
  int nW = (tid & 15) << 2;
  for (int k0 = 0; k0 < Kdim; k0 += 16) {
    float4 av = *(const float4*)(A + (size_t)(row0 + mA) * Kdim + k0 + kA);
    float4 wv = *(const float4*)(W + (size_t)(k0 + kW) * Ndim + col0 + nW);
    sA[kA + 0][mA] = av.x;
    sA[kA + 1][mA] = av.y;
    sA[kA + 2][mA] = av.z;
    sA[kA + 3][mA] = av.w;
    *(float4*)&sW[kW][nW] = wv;
    __syncthreads();
#pragma unroll
    for (int kk = 0; kk < 16; kk++) {
      float4 a = *(const float4*)&sA[kk][ty << 2];
      float4 b = *(const float4*)&sW[kk][tx << 2];
      acc[0][0] += a.x * b.x; acc[0][1] += a.x * b.y; acc[0][2] += a.x * b.z; acc[0][3] += a.x * b.w;
      acc[1][0] += a.y * b.x; acc[1][1] += a.y * b.y; acc[1][2] += a.y * b.z; acc[1][3] += a.y * b.w;
      acc[2][0] += a.z * b.x; acc[2][1] += a.z * b.y; acc[2][2] += a.z * b.z; acc[2][3] += a.z * b.w;
      acc[3][0] += a.w * b.x; acc[3][1] += a.w * b.y; acc[3][2] += a.w * b.z; acc[3][3] += a.w * b.w;
    }
    __syncthreads();
  }
#pragma unroll
  for (int i = 0; i < 4; i++) {
    int r = row0 + (ty << 2) + i;
#pragma unroll
    for (int jc = 0; jc < 4; jc++) {
      int c = col0 + (tx << 2) + jc;
      float o = acc[i][jc];
      if (bias) o += bias[c];
      if (act == 1) o = fmaxf(o, 0.f);
      else if (act == 2) o = (o >= 0.f) ? o : 0.01f * o;
      C[(size_t)r * Ndim + c] = o;
    }
  }
}

// ---------------------------------------------------------------------------
// Forward scan: block = quarter-row, coalesced list build.
// ---------------------------------------------------------------------------
__global__ __launch_bounds__(256) void scan_rows_kernel(
    const float* __restrict__ A, int* __restrict__ fcnt, int* __restrict__ fidx,
    float* __restrict__ fval, int* __restrict__ bcnt, int* __restrict__ bidx) {
  __shared__ int   lbuf[1024];
  __shared__ int   lcnt;
  __shared__ int   ecnt[EE];
  __shared__ int   en2[EE][ECAP];
  __shared__ float ev[EE][ECAP];
  __shared__ int   rbase;
  __shared__ int   gbase[EE];
  int tid = threadIdx.x;
  int n1 = blockIdx.x >> 2;
  int qb = (blockIdx.x & 3) << 10;
  if (tid == 0) lcnt = 0;
  if (tid < EE) ecnt[tid] = 0;
  __syncthreads();
  const float4* src = (const float4*)(A + ((size_t)n1 * NN + qb) * EE);
  float buf[20];
  float4* bf4 = (float4*)buf;
#pragma unroll
  for (int c = 0; c < 5; c++) bf4[c] = src[tid * 5 + c];
  int n2base = qb + tid * 4;
#pragma unroll
  for (int u = 0; u < 4; u++) {
    int n2 = n2base + u;
    if (n2 == n1) continue;
    bool any = false;
#pragma unroll
    for (int e = 0; e < EE; e++) {
      float v = buf[u * 5 + e];
      if (v != 0.f) {
        any = true;
        int s = atomicAdd(&ecnt[e], 1);
        if (s < ECAP) { en2[e][s] = n2; ev[e][s] = v; }
      }
    }
    if (any) {
      int s = atomicAdd(&lcnt, 1);
      lbuf[s] = n2;
    }
  }
  __syncthreads();
  if (tid == 0) rbase = atomicAdd(&bcnt[n1], lcnt);
  if (tid < EE) gbase[tid] = atomicAdd(&fcnt[tid * NN + n1], min(ecnt[tid], ECAP));
  __syncthreads();
  int c = lcnt, rb = rbase;
  for (int s = tid; s < c; s += 256)
    if (rb + s < BCAP) bidx[(size_t)n1 * BCAP + rb + s] = lbuf[s];
#pragma unroll
  for (int e = 0; e < EE; e++) {
    int ec = min(ecnt[e], ECAP), gb = gbase[e];
    size_t base = ((size_t)e * NN + n1) * GCAP;
    for (int s = tid; s < ec; s += 256) {
      if (gb + s < GCAP) {
        fidx[base + gb + s] = en2[e][s];
        fval[base + gb + s] = ev[e][s];
      }
    }
  }
}

// Forward -> transposed gcn lists (for lgcn).
__global__ __launch_bounds__(64) void transpose_kernel(
    const int* __restrict__ fcnt, const int* __restrict__ fidx, const float* __restrict__ fval,
    int* __restrict__ gcnt, int* __restrict__ gidx, float* __restrict__ gval) {
  int id = blockIdx.x;                      // e*NN + n1
  int n1 = id & (NN - 1);
  int e  = id >> 12;
  int c = min(fcnt[id], GCAP);
  for (int s = threadIdx.x; s < c; s += 64) {
    int   n2 = fidx[(size_t)id * GCAP + s];
    float v  = fval[(size_t)id * GCAP + s];
    int t = e * NN + n2;
    int slot = atomicAdd(&gcnt[t], 1);
    if (slot < GCAP) {
      gidx[(size_t)t * GCAP + slot] = n1;
      gval[(size_t)t * GCAP + slot] = v;
    }
  }
}

// dinv[e,i] = 1/(1 + sum gval)   ;   dis[i] = rsqrt(1 + bcnt[i])
__global__ void dinv_dis_kernel(const int* __restrict__ gcnt, const float* __restrict__ gval,
                                float* __restrict__ dinv, const int* __restrict__ bcnt,
                                float* __restrict__ dis) {
  int t = blockIdx.x * 256 + threadIdx.x;
  if (t < EE * NN) {
    int cnt = min(gcnt[t], GCAP);
    float s = 1.0f;
    for (int k = 0; k < cnt; k++) s += gval[(size_t)t * GCAP + k];
    dinv[t] = 1.0f / s;
  }
  if (t < NN) dis[t] = rsqrtf(1.0f + (float)min(bcnt[t], BCAP));
}

// ---------------------------------------------------------------------------
// Dense A_hat bf16 build: one block per row i; bitmap of neighbors in LDS,
// coalesced 8 KB row write. Ab[i][j] = (B[i][j]||i==j) ? dis[i]*dis[j] : 0.
// ---------------------------------------------------------------------------
__global__ __launch_bounds__(256) void build_ahat_kernel(
    const int* __restrict__ bcnt, const int* __restrict__ bidx,
    const float* __restrict__ dis, unsigned short* __restrict__ Ab) {
  __shared__ unsigned int bits[128];
  int i = blockIdx.x, t = threadIdx.x;
  if (t < 128) bits[t] = 0;
  __syncthreads();
  int cnt = min(bcnt[i], BCAP);
  for (int s = t; s < cnt; s += 256) {
    int j = bidx[(size_t)i * BCAP + s];
    atomicOr(&bits[j >> 5], 1u << (j & 31));
  }
  __syncthreads();
  float di = dis[i];
  int c0 = t * 16;
  unsigned short out[16];
#pragma unroll
  for (int u = 0; u < 16; u++) {
    int j = c0 + u;
    bool on = ((bits[j >> 5] >> (j & 31)) & 1u) || (j == i);
    out[u] = on ? f2bf(di * dis[j]) : (unsigned short)0;
  }
  *(ushort8_t*)&Ab[(size_t)i * NN + c0]     = *(ushort8_t*)&out[0];
  *(ushort8_t*)&Ab[(size_t)i * NN + c0 + 8] = *(ushort8_t*)&out[8];
}

// lgcn[e,i,d] = relu( dinv[e,i] * (Xw[i,d] + sum_s v_s * Xw[j_s,d]) )
__global__ __launch_bounds__(128) void lgcn_kernel(
    const int* __restrict__ gcnt, const int* __restrict__ gidx, const float* __restrict__ gval,
    const float* __restrict__ dinv, const float* __restrict__ Xw, float* __restrict__ lgcn) {
  int i = blockIdx.x, e = blockIdx.y, d = threadIdx.x;
  int t = e * NN + i;
  int cnt = min(gcnt[t], GCAP);
  __shared__ int   sj[GCAP];
  __shared__ float sv[GCAP];
  for (int s = d; s < cnt; s += 128) {
    sj[s] = gidx[(size_t)t * GCAP + s];
    sv[s] = gval[(size_t)t * GCAP + s];
  }
  __syncthreads();
  float acc = Xw[(size_t)i * WOUT + d];
  for (int s = 0; s < cnt; s++) acc += sv[s] * Xw[(size_t)sj[s] * WOUT + d];
  float r = dinv[t] * acc;
  lgcn[(size_t)t * WOUT + d] = fmaxf(r, 0.f);
}

__global__ void att_partial_kernel(const float* __restrict__ lgcn, const float* __restrict__ attw,
                                   float* __restrict__ tm_pre) {
  int e = blockIdx.y, d = threadIdx.x;
  int nbase = blockIdx.x * 128;
  float acc = 0.f;
  for (int k = 0; k < 128; k++) {
    int n = nbase + k;
    acc += attw[n] * lgcn[((size_t)(e * NN + n)) * WOUT + d];
  }
  atomicAdd(&tm_pre[e * WOUT + d], acc);
}

__global__ void att_final_kernel(const float* __restrict__ tm_pre, const float* __restrict__ attb,
                                 const float* __restrict__ attq, float* __restrict__ beta) {
  int lane = threadIdx.x;  // 64
  __shared__ float sw[EE];
  for (int e = 0; e < EE; e++) {
    float v = 0.f;
    for (int d = lane; d < WOUT; d += 64) {
      float tmv = tanhf(tm_pre[e * WOUT + d] + attb[d]);
      v += tmv * attq[d];
    }
    for (int off = 32; off; off >>= 1) v += __shfl_down(v, off, 64);
    if (lane == 0) sw[e] = v;
  }
  __syncthreads();
  if (lane == 0) {
    float mx = sw[0];
    for (int e = 1; e < EE; e++) mx = fmaxf(mx, sw[e]);
    float se = 0.f, ex[EE];
    for (int e = 0; e < EE; e++) { ex[e] = expf(sw[e] - mx); se += ex[e]; }
    for (int e = 0; e < EE; e++) beta[e] = ex[e] / se * (float)EE;
  }
}

__global__ void xcat_kernel(const float* __restrict__ lgcn, const float* __restrict__ X,
                            const float* __restrict__ beta, float* __restrict__ Xc) {
  int idx = blockIdx.x * 256 + threadIdx.x;
  const int total = NN * HH0;
  for (; idx < total; idx += gridDim.x * 256) {
    int n = idx / HH0, c = idx - n * HH0;
    float v;
    if (c < EE * WOUT) {
      int e = c >> 7, d = c & 127;
      v = beta[e] * lgcn[((size_t)(e * NN + n)) * WOUT + d];
    } else {
      v = X[(size_t)n * WIN + (c - EE * WOUT)];
    }
    Xc[idx] = v;
  }
}

// ---------------------------------------------------------------------------
// x (fp32 [NN][128]) -> xT (bf16 [128][NN]) via LDS transpose. 32 rows/block.
// ---------------------------------------------------------------------------
__global__ __launch_bounds__(256) void xT_convert_kernel(
    const float* __restrict__ x, unsigned short* __restrict__ xT) {
  __shared__ float sh2[128][36];    // [c][r]
  int r0 = blockIdx.x * 32, t = threadIdx.x;
  const float4* x4 = (const float4*)(x + (size_t)r0 * WOUT);
#pragma unroll
  for (int q = 0; q < 4; q++) {
    int lin = t + q * 256;          // float4 index in 32x128 tile
    int r = lin >> 5, c = (lin & 31) * 4;
    float4 v = x4[lin];
    sh2[c + 0][r] = v.x; sh2[c + 1][r] = v.y; sh2[c + 2][r] = v.z; sh2[c + 3][r] = v.w;
  }
  __syncthreads();
  int c = t >> 1, half = t & 1;
  unsigned short tmp[16];
#pragma unroll
  for (int rr = 0; rr < 16; rr++) tmp[rr] = f2bf(sh2[c][half * 16 + rr]);
  *(ushort8_t*)&xT[(size_t)c * NN + r0 + half * 16]     = *(ushort8_t*)&tmp[0];
  *(ushort8_t*)&xT[(size_t)c * NN + r0 + half * 16 + 8] = *(ushort8_t*)&tmp[8];
}

// ---------------------------------------------------------------------------
// Fully-fused GCNII layer, KSPLIT=1: one kernel per layer, no partial-sum
// buffer, no cross-block dependency, no fences. Grid 256 x 512 thr (8 waves).
// Block owns 16 output rows; wave = 16 rows x 16 cols (1 MFMA frag), full
// K=4096 accumulated in fp32. Pipeline = R3-verified: double-buffered BK=64
// tiles (two BK=32 sub-tiles, 64B rows -> conflict-free ds_read_b128),
// global_load_lds w16 staging (18 x 1KB chunks/tile across 8 waves),
// STAGE(next) before compute(cur), vmcnt(0)+barrier per tile.
// Epilogue in-block: h = 0.9*S + 0.1*x0 -> LDS[col][row]; o = h@Wl;
// y = relu((1-bl)h + bl*o); bf16 transposed write (+f32 last layer).
// Layouts (m89/m91-verified): A-frag A[m=lane&15][k=quad*8+j];
// B-frag B[k=quad*8+j][n=lane&15]; C/D col=lane&15,row=quad*4+reg.
// ---------------------------------------------------------------------------
__global__ __launch_bounds__(512) void gcnii_fused_kernel(
    const unsigned short* __restrict__ Ab, const unsigned short* __restrict__ xbT,
    const float* __restrict__ x0, const float* __restrict__ Wl, float bl,
    float* __restrict__ xout_f32, unsigned short* __restrict__ xoutT, int write_f32) {
  // per buffer 9216 shorts: A [2sub][16r][32k] at 0..1023; X [2sub][128r][32k] at 1024..
  __shared__ __align__(16) unsigned short sT[2][9216];
  __shared__ float sh2[128][22];   // [col][row] epi buffer
  int t = threadIdx.x;
  int wave = t >> 6, lane = t & 63;
  int r0 = blockIdx.x * 16;
  int wc = wave * 16;
  int quad = lane >> 4, mrow = lane & 15;
  f32x4_t acc = {0.f, 0.f, 0.f, 0.f};

  // staging chunks: 18 total (A:2 @ c<2, X:16 @ c-2), wave w takes c = w, w+8, w+16
  const unsigned short* gq[3];
  int lq[3];
#pragma unroll
  for (int q = 0; q < 3; q++) {
    int c = wave + q * 8;
    if (c < 2) {
      gq[q] = Ab + (size_t)(r0 + (lane >> 2)) * NN + c * 32 + (lane & 3) * 8;
      lq[q] = c * 512;
    } else if (c < 18) {
      int cc = c - 2;
      int sub = cc >> 3, rb = cc & 7;
      gq[q] = xbT + (size_t)(rb * 16 + (lane >> 2)) * NN + sub * 32 + (lane & 3) * 8;
      lq[q] = 1024 + sub * 4096 + rb * 512;
    } else {
      gq[q] = Ab;  // never used (guarded below)
      lq[q] = 0;
    }
  }
  int nq3 = (wave < 2) ? 1 : 0;

#define STAGE(BUF, TS)                                           \
  {                                                              \
    unsigned short* lb = &sT[(BUF)][0];                          \
    gload16(gq[0] + (size_t)(TS) * 64, lb + lq[0]);              \
    gload16(gq[1] + (size_t)(TS) * 64, lb + lq[1]);              \
    if (nq3) gload16(gq[2] + (size_t)(TS) * 64, lb + lq[2]);     \
  }

  STAGE(0, 0);
  asm volatile("s_waitcnt vmcnt(0)" ::: "memory");
  __builtin_amdgcn_s_barrier();

  int cur = 0;
  for (int tt = 0; tt < 64; tt++) {
    if (tt < 63) STAGE(cur ^ 1, tt + 1);
    const unsigned short* base = &sT[cur][0];
    bf16x8_t af0 = *(const bf16x8_t*)&base[mrow * 32 + quad * 8];
    bf16x8_t af1 = *(const bf16x8_t*)&base[512 + mrow * 32 + quad * 8];
    bf16x8_t bf0 = *(const bf16x8_t*)&base[1024 + (wc + mrow) * 32 + quad * 8];
    bf16x8_t bf1 = *(const bf16x8_t*)&base[1024 + 4096 + (wc + mrow) * 32 + quad * 8];
    acc = __builtin_amdgcn_mfma_f32_16x16x32_bf16(af0, bf0, acc, 0, 0, 0);
    acc = __builtin_amdgcn_mfma_f32_16x16x32_bf16(af1, bf1, acc, 0, 0, 0);
    if (tt < 63) {
      asm volatile("s_waitcnt vmcnt(0)" ::: "memory");  // next-tile loads landed
      __builtin_amdgcn_s_barrier();                      // reads done, writes visible
      cur ^= 1;
    }
  }
#undef STAGE

  // ---- in-block GCNII epilogue ----
  // h = 0.9*S + 0.1*x0 -> sh2[col][row]
#pragma unroll
  for (int r4 = 0; r4 < 4; r4++) {
    int row = quad * 4 + r4;
    float xv = x0[(size_t)(r0 + row) * WOUT + wc + mrow];
    sh2[wc + mrow][row] = 0.9f * acc[r4] + 0.1f * xv;
  }
  __syncthreads();
  // o = h@Wl : thread = (row ty2, cols tx2*4..+3)
  int tx2 = t & 31, ty2 = t >> 5;   // 32 col-groups x 16 rows
  float o0 = 0.f, o1 = 0.f, o2 = 0.f, o3 = 0.f;
  const float* wp = Wl + tx2 * 4;
  for (int k = 0; k < WOUT; k++) {
    float aa = sh2[k][ty2];
    float4 w = *(const float4*)(wp + k * WOUT);
    o0 = fmaf(aa, w.x, o0);
    o1 = fmaf(aa, w.y, o1);
    o2 = fmaf(aa, w.z, o2);
    o3 = fmaf(aa, w.w, o3);
  }
  float c1 = 1.f - bl;
  float h0 = sh2[tx2 * 4 + 0][ty2];
  float h1 = sh2[tx2 * 4 + 1][ty2];
  float h2 = sh2[tx2 * 4 + 2][ty2];
  float h3 = sh2[tx2 * 4 + 3][ty2];
  float y0 = fmaxf(c1 * h0 + bl * o0, 0.f);
  float y1 = fmaxf(c1 * h1 + bl * o1, 0.f);
  float y2 = fmaxf(c1 * h2 + bl * o2, 0.f);
  float y3 = fmaxf(c1 * h3 + bl * o3, 0.f);
  if (write_f32) {
    float4 v = {y0, y1, y2, y3};
    *(float4*)&xout_f32[(size_t)(r0 + ty2) * WOUT + tx2 * 4] = v;
  }
  __syncthreads();   // done reading sh2 as h
  sh2[tx2 * 4 + 0][ty2] = y0;
  sh2[tx2 * 4 + 1][ty2] = y1;
  sh2[tx2 * 4 + 2][ty2] = y2;
  sh2[tx2 * 4 + 3][ty2] = y3;
  __syncthreads();
  // transposed bf16 write: threads 0..255, col cc, 8 rows each
  if (t < 256) {
    int cc = t >> 1, half = t & 1;
    unsigned short tmp[8];
#pragma unroll
    for (int rr = 0; rr < 8; rr++) tmp[rr] = f2bf(sh2[cc][half * 8 + rr]);
    *(ushort8_t*)&xoutT[(size_t)cc * NN + r0 + half * 8] = *(ushort8_t*)&tmp[0];
  }
}

// y = Z[tx]@W2 + b2 ; per-row log-softmax ; per-block loss partials
__global__ __launch_bounds__(256) void head_kernel(
    const float* __restrict__ Z, const int* __restrict__ txv, const int* __restrict__ tgt,
    const float* __restrict__ W2, const float* __restrict__ b2,
    float* __restrict__ out_y, float* __restrict__ lossp) {
  int tid = threadIdx.x;
  int mr = tid >> 4, c = tid & 15;
  int m = blockIdx.x * 16 + mr;
  const float* zr = Z + (size_t)txv[m] * WOUT;
  float acc = b2[c];
  for (int k = 0; k < WOUT; k++) acc += zr[k] * W2[k * NCLS + c];
  out_y[(size_t)m * NCLS + c] = acc;
  float mx = acc;
  for (int off = 8; off; off >>= 1) mx = fmaxf(mx, __shfl_xor(mx, off, 16));
  float ex = expf(acc - mx);
  float se = ex;
  for (int off = 8; off; off >>= 1) se += __shfl_xor(se, off, 16);
  float lse = mx + logf(se);
  float contrib = (c == tgt[m]) ? (lse - acc) : 0.f;
  __shared__ float red[256];
  red[tid] = contrib;
  __syncthreads();
  for (int stp = 128; stp; stp >>= 1) {
    if (tid < stp) red[tid] += red[tid + stp];
    __syncthreads();
  }
  if (tid == 0) lossp[blockIdx.x] = red[0];
}

__global__ void loss_final_kernel(const float* __restrict__ lossp, float* __restrict__ out_loss) {
  int lane = threadIdx.x;
  float v = (lane < 64) ? lossp[lane] : 0.f;
  for (int off = 32; off; off >>= 1) v += __shfl_down(v, off, 64);
  if (lane == 0) out_loss[0] = v / (float)MT;
}

// ---------------------------------------------------------------------------
extern "C" void kernel_launch(void* const* d_in, const int* in_sizes, int n_in,
                              void* d_out, int out_size, void* d_ws, size_t ws_size,
                              hipStream_t stream) {
  const float* A      = (const float*)d_in[0];
  const float* X      = (const float*)d_in[1];
  const int*   txv    = (const int*)d_in[2];
  const int*   tgt    = (const int*)d_in[3];
  const float* weight = (const float*)d_in[4];
  const float* attw   = (const float*)d_in[5];
  const float* attb   = (const float*)d_in[6];
  const float* attq   = (const float*)d_in[7];
  const float* Wg     = (const float*)d_in[8];
  const float* bg     = (const float*)d_in[9];
  const float* W0     = (const float*)d_in[10];
  const float* b0     = (const float*)d_in[11];
  const float* Wconvs = (const float*)d_in[12];
  const float* Wd1    = (const float*)d_in[13];
  const float* bd1    = (const float*)d_in[14];
  const float* W1     = (const float*)d_in[15];
  const float* b1     = (const float*)d_in[16];
  const float* W2     = (const float*)d_in[17];
  const float* b2     = (const float*)d_in[18];

  float* ws  = (float*)d_ws;
  int*   wsi = (int*)d_ws;

  // offsets in 4-byte units (ws >= 1.3 GB per harness poison)
  const size_t O_GCNT  = 0;                         // 20480 ints
  const size_t O_BCNT  = 20480;                     // 4096
  const size_t O_FCNT  = 24576;                     // 20480
  const size_t O_DINV  = 45056;                     // 20480
  const size_t O_DIS   = 65536;                     // 4096
  const size_t O_TMPRE = 69632;                     // 640
  const size_t O_BETA  = 70272;                     // 16
  const size_t O_LOSSP = 70288;                     // 64
  const size_t O_GIDX  = 71680;                     // 1966080
  const size_t O_GVAL  = O_GIDX + 1966080;
  const size_t O_FIDX  = O_GVAL + 1966080;
  const size_t O_FVAL  = O_FIDX + 1966080;
  const size_t O_BIDX  = O_FVAL + 1966080;          // 1310720
  const size_t O_LGCN  = O_BIDX + 1310720;          // 2621440
  const size_t O_XW    = O_LGCN + 2621440;          // 524288
  const size_t O_X0    = O_XW   + 524288;           // 524288
  const size_t O_XA    = O_X0   + 524288;           // 524288
  const size_t O_XB    = O_XA   + 524288;           // 524288
  const size_t O_AB    = O_XB   + 524288;           // 8388608 (4096x4096 bf16)
  const size_t O_XBT0  = O_AB   + 8388608;          // 262144  (128x4096 bf16)
  const size_t O_XBT1  = O_XBT0 + 262144;           // 262144
  // aliases (lifetimes verified by launch order):
  const size_t O_T1    = O_FVAL;   // [4096,512] dead before scan writes fval/bidx
  const size_t O_XCAT  = O_GIDX;   // [4096,1152] built after gidx/gval/fidx last reads

  hipMemsetAsync(ws + O_GCNT, 0, 45056 * 4, stream);   // gcnt+bcnt+fcnt
  hipMemsetAsync(ws + O_TMPRE, 0, 640 * 4, stream);

  dim3 blk(256);
  // Stage A: Xw = leaky(leaky(X@Wg+bg)@weight)
  gemm_kernel<<<dim3(WIN / 64, NN / 64), blk, 0, stream>>>(X, Wg, bg, ws + O_T1, NN, WIN, WIN, 2);
  gemm_kernel<<<dim3(WOUT / 64, NN / 64), blk, 0, stream>>>(ws + O_T1, weight, nullptr, ws + O_XW, NN, WIN, WOUT, 2);
  // Stage B: sparse structures + dense A_hat
  scan_rows_kernel<<<NN * 4, 256, 0, stream>>>(A, wsi + O_FCNT, wsi + O_FIDX, ws + O_FVAL,
                                               wsi + O_BCNT, wsi + O_BIDX);
  transpose_kernel<<<EE * NN, 64, 0, stream>>>(wsi + O_FCNT, wsi + O_FIDX, ws + O_FVAL,
                                               wsi + O_GCNT, wsi + O_GIDX, ws + O_GVAL);
  dinv_dis_kernel<<<80, 256, 0, stream>>>(wsi + O_GCNT, ws + O_GVAL, ws + O_DINV,
                                          wsi + O_BCNT, ws + O_DIS);
  build_ahat_kernel<<<NN, 256, 0, stream>>>(wsi + O_BCNT, wsi + O_BIDX, ws + O_DIS,
                                            (unsigned short*)(ws + O_AB));
  // Stage C: lgcn
  lgcn_kernel<<<dim3(NN, EE), 128, 0, stream>>>(wsi + O_GCNT, wsi + O_GIDX, ws + O_GVAL,
                                                ws + O_DINV, ws + O_XW, ws + O_LGCN);
  // Stage D: attention -> beta
  att_partial_kernel<<<dim3(32, EE), 128, 0, stream>>>(ws + O_LGCN, attw, ws + O_TMPRE);
  att_final_kernel<<<1, 64, 0, stream>>>(ws + O_TMPRE, attb, attq, ws + O_BETA);
  // Stage E: X_ and x0
  xcat_kernel<<<4096, 256, 0, stream>>>(ws + O_LGCN, X, ws + O_BETA, ws + O_XCAT);
  gemm_kernel<<<dim3(WOUT / 64, NN / 64), blk, 0, stream>>>(ws + O_XCAT, W0, b0, ws + O_X0, NN, HH0, WOUT, 1);
  xT_convert_kernel<<<NN / 32, 256, 0, stream>>>(ws + O_X0, (unsigned short*)(ws + O_XBT0));
  // Stage F: 64 GCNII layers, ONE fused kernel per layer (KSPLIT=1, no P)
  for (int l = 0; l < NLAY; l++) {
    float bl = logf(0.5f / (float)(l + 1) + 1.0f);
    const unsigned short* xin = (const unsigned short*)(ws + ((l & 1) ? O_XBT1 : O_XBT0));
    unsigned short* xoT = (unsigned short*)(ws + ((l & 1) ? O_XBT0 : O_XBT1));
    gcnii_fused_kernel<<<NN / 16, 512, 0, stream>>>(
        (const unsigned short*)(ws + O_AB), xin, ws + O_X0,
        Wconvs + (size_t)l * WOUT * WOUT, bl,
        ws + O_XA, xoT, (l == NLAY - 1) ? 1 : 0);
  }
  // Stage G: head (fp32 x in O_XA)
  gemm_kernel<<<dim3(WOUT / 64, NN / 64), blk, 0, stream>>>(ws + O_XA, Wd1, bd1, ws + O_XB, NN, WOUT, WOUT, 2);
  gemm_kernel<<<dim3(WOUT / 64, NN / 64), blk, 0, stream>>>(ws + O_XB, W1, b1, ws + O_X0, NN, WOUT, WOUT, 2);
  head_kernel<<<MT / 16, 256, 0, stream>>>(ws + O_X0, txv, tgt, W2, b2,
                                           (float*)d_out + 1, ws + O_LOSSP);
  loss_final_kernel<<<1, 64, 0, stream>>>(ws + O_LOSSP, (float*)d_out);
}

// Round 9
// 2388.594 us; speedup vs baseline: 2.9521x; 1.4673x over previous
//
#include <hip/hip_runtime.h>
#include <cstdint>
#include <cmath>

#define NN   4096
#define EE   5
#define WIN  512
#define WOUT 128
#define HH0  1152   // WIN + EE*WOUT
#define NLAY 64
#define NCLS 16
#define MT   1024
#define GCAP 96     // per-(e,node) list cap; Binomial(4096,0.01) max ~70
#define BCAP 320    // per-node union cap; Binomial(4096,0.049) max ~260
#define ECAP 48     // per-(e, quarter-row) cap
#define KSPLIT 8
#define KCHUNK 512  // KSPLIT*KCHUNK == NN
#define NTILE  8    // KCHUNK / 64

typedef __attribute__((ext_vector_type(8))) short     bf16x8_t;
typedef __attribute__((ext_vector_type(8))) unsigned short ushort8_t;
typedef __attribute__((ext_vector_type(4))) float     f32x4_t;

__device__ inline unsigned short f2bf(float f) {
  unsigned int u = __float_as_uint(f);
  unsigned int r = (u + 0x7FFFu + ((u >> 16) & 1u)) >> 16;  // RNE
  return (unsigned short)r;
}

// async global->LDS, 16B per lane: dest = lds_base(wave-uniform) + lane*16
__device__ __forceinline__ void gload16(const unsigned short* g, unsigned short* l) {
  __builtin_amdgcn_global_load_lds(
      (__attribute__((address_space(1))) void*)g,
      (__attribute__((address_space(3))) void*)l, 16, 0, 0);
}

// ---------------------------------------------------------------------------
// Generic register-tiled fp32 GEMM: C = act(A[M,K] @ W[K,N] + bias)
// 64x64 tile, 256 threads, 4x4 outputs/thread, BK=16. act:0=none,1=relu,2=leaky
// ---------------------------------------------------------------------------
__global__ __launch_bounds__(256) void gemm_kernel(
    const float* __restrict__ A, const float* __restrict__ W,
    const float* __restrict__ bias, float* __restrict__ C,
    int Mdim, int Kdim, int Ndim, int act) {
  __shared__ __align__(16) float sA[16][68];
  __shared__ __align__(16) float sW[16][64];
  int tid = threadIdx.x;
  int tx = tid & 15, ty = tid >> 4;
  int row0 = blockIdx.y * 64, col0 = blockIdx.x * 64;
  float acc[4][4] = {};
  int mA = tid >> 2;
  int kA = (tid & 3) << 2;
  int kW = tid >> 4;
  int nW = (tid & 15) << 2;
  for (int k0 = 0; k0 < Kdim; k0 += 16) {
    float4 av = *(const float4*)(A + (size_t)(row0 + mA) * Kdim + k0 + kA);
    float4 wv = *(const float4*)(W + (size_t)(k0 + kW) * Ndim + col0 + nW);
    sA[kA + 0][mA] = av.x;
    sA[kA + 1][mA] = av.y;
    sA[kA + 2][mA] = av.z;
    sA[kA + 3][mA] = av.w;
    *(float4*)&sW[kW][nW] = wv;
    __syncthreads();
#pragma unroll
    for (int kk = 0; kk < 16; kk++) {
      float4 a = *(const float4*)&sA[kk][ty << 2];
      float4 b = *(const float4*)&sW[kk][tx << 2];
      acc[0][0] += a.x * b.x; acc[0][1] += a.x * b.y; acc[0][2] += a.x * b.z; acc[0][3] += a.x * b.w;
      acc[1][0] += a.y * b.x; acc[1][1] += a.y * b.y; acc[1][2] += a.y * b.z; acc[1][3] += a.y * b.w;
      acc[2][0] += a.z * b.x; acc[2][1] += a.z * b.y; acc[2][2] += a.z * b.z; acc[2][3] += a.z * b.w;
      acc[3][0] += a.w * b.x; acc[3][1] += a.w * b.y; acc[3][2] += a.w * b.z; acc[3][3] += a.w * b.w;
    }
    __syncthreads();
  }
#pragma unroll
  for (int i = 0; i < 4; i++) {
    int r = row0 + (ty << 2) + i;
#pragma unroll
    for (int jc = 0; jc < 4; jc++) {
      int c = col0 + (tx << 2) + jc;
      float o = acc[i][jc];
      if (bias) o += bias[c];
      if (act == 1) o = fmaxf(o, 0.f);
      else if (act == 2) o = (o >= 0.f) ? o : 0.01f * o;
      C[(size_t)r * Ndim + c] = o;
    }
  }
}

// ---------------------------------------------------------------------------
// Forward scan: block = quarter-row, coalesced list build.
// ---------------------------------------------------------------------------
__global__ __launch_bounds__(256) void scan_rows_kernel(
    const float* __restrict__ A, int* __restrict__ fcnt, int* __restrict__ fidx,
    float* __restrict__ fval, int* __restrict__ bcnt, int* __restrict__ bidx) {
  __shared__ int   lbuf[1024];
  __shared__ int   lcnt;
  __shared__ int   ecnt[EE];
  __shared__ int   en2[EE][ECAP];
  __shared__ float ev[EE][ECAP];
  __shared__ int   rbase;
  __shared__ int   gbase[EE];
  int tid = threadIdx.x;
  int n1 = blockIdx.x >> 2;
  int qb = (blockIdx.x & 3) << 10;
  if (tid == 0) lcnt = 0;
  if (tid < EE) ecnt[tid] = 0;
  __syncthreads();
  const float4* src = (const float4*)(A + ((size_t)n1 * NN + qb) * EE);
  float buf[20];
  float4* bf4 = (float4*)buf;
#pragma unroll
  for (int c = 0; c < 5; c++) bf4[c] = src[tid * 5 + c];
  int n2base = qb + tid * 4;
#pragma unroll
  for (int u = 0; u < 4; u++) {
    int n2 = n2base + u;
    if (n2 == n1) continue;
    bool any = false;
#pragma unroll
    for (int e = 0; e < EE; e++) {
      float v = buf[u * 5 + e];
      if (v != 0.f) {
        any = true;
        int s = atomicAdd(&ecnt[e], 1);
        if (s < ECAP) { en2[e][s] = n2; ev[e][s] = v; }
      }
    }
    if (any) {
      int s = atomicAdd(&lcnt, 1);
      lbuf[s] = n2;
    }
  }
  __syncthreads();
  if (tid == 0) rbase = atomicAdd(&bcnt[n1], lcnt);
  if (tid < EE) gbase[tid] = atomicAdd(&fcnt[tid * NN + n1], min(ecnt[tid], ECAP));
  __syncthreads();
  int c = lcnt, rb = rbase;
  for (int s = tid; s < c; s += 256)
    if (rb + s < BCAP) bidx[(size_t)n1 * BCAP + rb + s] = lbuf[s];
#pragma unroll
  for (int e = 0; e < EE; e++) {
    int ec = min(ecnt[e], ECAP), gb = gbase[e];
    size_t base = ((size_t)e * NN + n1) * GCAP;
    for (int s = tid; s < ec; s += 256) {
      if (gb + s < GCAP) {
        fidx[base + gb + s] = en2[e][s];
        fval[base + gb + s] = ev[e][s];
      }
    }
  }
}

// Forward -> transposed gcn lists (for lgcn).
__global__ __launch_bounds__(64) void transpose_kernel(
    const int* __restrict__ fcnt, const int* __restrict__ fidx, const float* __restrict__ fval,
    int* __restrict__ gcnt, int* __restrict__ gidx, float* __restrict__ gval) {
  int id = blockIdx.x;                      // e*NN + n1
  int n1 = id & (NN - 1);
  int e  = id >> 12;
  int c = min(fcnt[id], GCAP);
  for (int s = threadIdx.x; s < c; s += 64) {
    int   n2 = fidx[(size_t)id * GCAP + s];
    float v  = fval[(size_t)id * GCAP + s];
    int t = e * NN + n2;
    int slot = atomicAdd(&gcnt[t], 1);
    if (slot < GCAP) {
      gidx[(size_t)t * GCAP + slot] = n1;
      gval[(size_t)t * GCAP + slot] = v;
    }
  }
}

// dinv[e,i] = 1/(1 + sum gval)   ;   dis[i] = rsqrt(1 + bcnt[i])
__global__ void dinv_dis_kernel(const int* __restrict__ gcnt, const float* __restrict__ gval,
                                float* __restrict__ dinv, const int* __restrict__ bcnt,
                                float* __restrict__ dis) {
  int t = blockIdx.x * 256 + threadIdx.x;
  if (t < EE * NN) {
    int cnt = min(gcnt[t], GCAP);
    float s = 1.0f;
    for (int k = 0; k < cnt; k++) s += gval[(size_t)t * GCAP + k];
    dinv[t] = 1.0f / s;
  }
  if (t < NN) dis[t] = rsqrtf(1.0f + (float)min(bcnt[t], BCAP));
}

// ---------------------------------------------------------------------------
// Dense A_hat bf16 build: one block per row i; bitmap of neighbors in LDS,
// coalesced 8 KB row write. Ab[i][j] = (B[i][j]||i==j) ? dis[i]*dis[j] : 0.
// ---------------------------------------------------------------------------
__global__ __launch_bounds__(256) void build_ahat_kernel(
    const int* __restrict__ bcnt, const int* __restrict__ bidx,
    const float* __restrict__ dis, unsigned short* __restrict__ Ab) {
  __shared__ unsigned int bits[128];
  int i = blockIdx.x, t = threadIdx.x;
  if (t < 128) bits[t] = 0;
  __syncthreads();
  int cnt = min(bcnt[i], BCAP);
  for (int s = t; s < cnt; s += 256) {
    int j = bidx[(size_t)i * BCAP + s];
    atomicOr(&bits[j >> 5], 1u << (j & 31));
  }
  __syncthreads();
  float di = dis[i];
  int c0 = t * 16;
  unsigned short out[16];
#pragma unroll
  for (int u = 0; u < 16; u++) {
    int j = c0 + u;
    bool on = ((bits[j >> 5] >> (j & 31)) & 1u) || (j == i);
    out[u] = on ? f2bf(di * dis[j]) : (unsigned short)0;
  }
  *(ushort8_t*)&Ab[(size_t)i * NN + c0]     = *(ushort8_t*)&out[0];
  *(ushort8_t*)&Ab[(size_t)i * NN + c0 + 8] = *(ushort8_t*)&out[8];
}

// lgcn[e,i,d] = relu( dinv[e,i] * (Xw[i,d] + sum_s v_s * Xw[j_s,d]) )
__global__ __launch_bounds__(128) void lgcn_kernel(
    const int* __restrict__ gcnt, const int* __restrict__ gidx, const float* __restrict__ gval,
    const float* __restrict__ dinv, const float* __restrict__ Xw, float* __restrict__ lgcn) {
  int i = blockIdx.x, e = blockIdx.y, d = threadIdx.x;
  int t = e * NN + i;
  int cnt = min(gcnt[t], GCAP);
  __shared__ int   sj[GCAP];
  __shared__ float sv[GCAP];
  for (int s = d; s < cnt; s += 128) {
    sj[s] = gidx[(size_t)t * GCAP + s];
    sv[s] = gval[(size_t)t * GCAP + s];
  }
  __syncthreads();
  float acc = Xw[(size_t)i * WOUT + d];
  for (int s = 0; s < cnt; s++) acc += sv[s] * Xw[(size_t)sj[s] * WOUT + d];
  float r = dinv[t] * acc;
  lgcn[(size_t)t * WOUT + d] = fmaxf(r, 0.f);
}

__global__ void att_partial_kernel(const float* __restrict__ lgcn, const float* __restrict__ attw,
                                   float* __restrict__ tm_pre) {
  int e = blockIdx.y, d = threadIdx.x;
  int nbase = blockIdx.x * 128;
  float acc = 0.f;
  for (int k = 0; k < 128; k++) {
    int n = nbase + k;
    acc += attw[n] * lgcn[((size_t)(e * NN + n)) * WOUT + d];
  }
  atomicAdd(&tm_pre[e * WOUT + d], acc);
}

__global__ void att_final_kernel(const float* __restrict__ tm_pre, const float* __restrict__ attb,
                                 const float* __restrict__ attq, float* __restrict__ beta) {
  int lane = threadIdx.x;  // 64
  __shared__ float sw[EE];
  for (int e = 0; e < EE; e++) {
    float v = 0.f;
    for (int d = lane; d < WOUT; d += 64) {
      float tmv = tanhf(tm_pre[e * WOUT + d] + attb[d]);
      v += tmv * attq[d];
    }
    for (int off = 32; off; off >>= 1) v += __shfl_down(v, off, 64);
    if (lane == 0) sw[e] = v;
  }
  __syncthreads();
  if (lane == 0) {
    float mx = sw[0];
    for (int e = 1; e < EE; e++) mx = fmaxf(mx, sw[e]);
    float se = 0.f, ex[EE];
    for (int e = 0; e < EE; e++) { ex[e] = expf(sw[e] - mx); se += ex[e]; }
    for (int e = 0; e < EE; e++) beta[e] = ex[e] / se * (float)EE;
  }
}

__global__ void xcat_kernel(const float* __restrict__ lgcn, const float* __restrict__ X,
                            const float* __restrict__ beta, float* __restrict__ Xc) {
  int idx = blockIdx.x * 256 + threadIdx.x;
  const int total = NN * HH0;
  for (; idx < total; idx += gridDim.x * 256) {
    int n = idx / HH0, c = idx - n * HH0;
    float v;
    if (c < EE * WOUT) {
      int e = c >> 7, d = c & 127;
      v = beta[e] * lgcn[((size_t)(e * NN + n)) * WOUT + d];
    } else {
      v = X[(size_t)n * WIN + (c - EE * WOUT)];
    }
    Xc[idx] = v;
  }
}

// ---------------------------------------------------------------------------
// x (fp32 [NN][128]) -> xT (bf16 [128][NN]) via LDS transpose. 32 rows/block.
// ---------------------------------------------------------------------------
__global__ __launch_bounds__(256) void xT_convert_kernel(
    const float* __restrict__ x, unsigned short* __restrict__ xT) {
  __shared__ float sh2[128][36];    // [c][r]
  int r0 = blockIdx.x * 32, t = threadIdx.x;
  const float4* x4 = (const float4*)(x + (size_t)r0 * WOUT);
#pragma unroll
  for (int q = 0; q < 4; q++) {
    int lin = t + q * 256;          // float4 index in 32x128 tile
    int r = lin >> 5, c = (lin & 31) * 4;
    float4 v = x4[lin];
    sh2[c + 0][r] = v.x; sh2[c + 1][r] = v.y; sh2[c + 2][r] = v.z; sh2[c + 3][r] = v.w;
  }
  __syncthreads();
  int c = t >> 1, half = t & 1;
  unsigned short tmp[16];
#pragma unroll
  for (int rr = 0; rr < 16; rr++) tmp[rr] = f2bf(sh2[c][half * 16 + rr]);
  *(ushort8_t*)&xT[(size_t)c * NN + r0 + half * 16]     = *(ushort8_t*)&tmp[0];
  *(ushort8_t*)&xT[(size_t)c * NN + r0 + half * 16 + 8] = *(ushort8_t*)&tmp[8];
}

// ---------------------------------------------------------------------------
// SpMM-as-dense-GEMM, bf16 MFMA 16x16x32. Block: 64 rows x 128 cols,
// K-chunk 512 (split-K 8). Grid 64x8=512 blocks (2/CU). 4 waves, each a
// 32x64 sub-tile (2x4 MFMA tiles). Double-buffered BK=64 stages (two BK=32
// sub-tiles, 64B rows -> contiguous conflict-free ds_read_b128),
// global_load_lds width=16 staging via 6 precomputed chunk descriptors per
// wave (24 x 1KB chunks per tile).
// LDS per buffer: A[2][64][32] (8KB) then X[2][128][32] (16KB) = 12288 shorts.
// Layouts (m89/m91-verified): A-frag A[m=lane&15][k=quad*8+j];
// B-frag B[k=quad*8+j][n=lane&15]; C/D col=lane&15,row=quad*4+reg.
// ---------------------------------------------------------------------------
__global__ __launch_bounds__(256) void spmm_kernel(
    const unsigned short* __restrict__ Ab, const unsigned short* __restrict__ xbT,
    float* __restrict__ P) {
  __shared__ __align__(16) unsigned short sT[2][12288];
  int t = threadIdx.x;
  int rt = blockIdx.x & 63, kc = blockIdx.x >> 6;
  int r0 = rt * 64, k0 = kc * KCHUNK;
  int wave = t >> 6, lane = t & 63;
  int wr = (wave & 1) * 32, wc = (wave >> 1) * 64;
  int quad = lane >> 4, mrow = lane & 15;
  f32x4_t acc[2][4] = {};

  // 6 staging chunks per wave; chunk = 16 rows x 64B. c<8: A, else X.
  const unsigned short* gq[6];
  int lq[6];
#pragma unroll
  for (int q = 0; q < 6; q++) {
    int c = wave * 6 + q;
    if (c < 8) {
      int sub = c >> 2, rb = c & 3;
      gq[q] = Ab + (size_t)(r0 + rb * 16 + (lane >> 2)) * NN + k0 + sub * 32 + (lane & 3) * 8;
      lq[q] = sub * 2048 + rb * 512;
    } else {
      int cc = c - 8;
      int sub = cc >> 3, rb = cc & 7;
      gq[q] = xbT + (size_t)(rb * 16 + (lane >> 2)) * NN + k0 + sub * 32 + (lane & 3) * 8;
      lq[q] = 4096 + sub * 4096 + rb * 512;
    }
  }

#define STAGE(BUF, TS)                                         \
  {                                                            \
    unsigned short* lb = &sT[(BUF)][0];                        \
    _Pragma("unroll")                                          \
    for (int q = 0; q < 6; q++)                                \
      gload16(gq[q] + (TS) * 64, lb + lq[q]);                  \
  }

  STAGE(0, 0);
  asm volatile("s_waitcnt vmcnt(0)" ::: "memory");
  __builtin_amdgcn_s_barrier();

  int cur = 0;
  for (int tt = 0; tt < NTILE; tt++) {
    if (tt < NTILE - 1) STAGE(cur ^ 1, tt + 1);
    const unsigned short* base = &sT[cur][0];
    bf16x8_t af[2][2], bfv[2][4];
#pragma unroll
    for (int kk = 0; kk < 2; kk++) {
#pragma unroll
      for (int mi = 0; mi < 2; mi++)
        af[kk][mi] = *(const bf16x8_t*)&base[kk * 2048 + (wr + mi * 16 + mrow) * 32 + quad * 8];
#pragma unroll
      for (int nj = 0; nj < 4; nj++)
        bfv[kk][nj] = *(const bf16x8_t*)&base[4096 + kk * 4096 + (wc + nj * 16 + mrow) * 32 + quad * 8];
    }
#pragma unroll
    for (int kk = 0; kk < 2; kk++)
#pragma unroll
      for (int mi = 0; mi < 2; mi++)
#pragma unroll
        for (int nj = 0; nj < 4; nj++)
          acc[mi][nj] = __builtin_amdgcn_mfma_f32_16x16x32_bf16(af[kk][mi], bfv[kk][nj], acc[mi][nj], 0, 0, 0);
    if (tt < NTILE - 1) {
      asm volatile("s_waitcnt vmcnt(0)" ::: "memory");  // next-tile loads landed
      __builtin_amdgcn_s_barrier();                      // reads done, writes visible
      cur ^= 1;
    }
  }
#undef STAGE

  float* Pk = P + (size_t)kc * (NN * WOUT);
#pragma unroll
  for (int mi = 0; mi < 2; mi++)
#pragma unroll
    for (int nj = 0; nj < 4; nj++) {
#pragma unroll
      for (int r4 = 0; r4 < 4; r4++) {
        int row = r0 + wr + mi * 16 + quad * 4 + r4;
        int col = wc + nj * 16 + mrow;
        Pk[(size_t)row * WOUT + col] = acc[mi][nj][r4];
      }
    }
}

// ---------------------------------------------------------------------------
// GCNII epilogue: h = sum_kc P + residual; y = relu((1-bl)h + bl*h@Wl);
// writes xT bf16 (always) and x fp32 (last layer).
// 16 rows/block -> 256 blocks (full chip), 256 thr, 2x4 outputs/thread.
// ---------------------------------------------------------------------------
__global__ __launch_bounds__(256) void gcnii_epi_kernel(
    const float* __restrict__ P, const float* __restrict__ x0,
    const float* __restrict__ Wl, float bl,
    float* __restrict__ xout_f32, unsigned short* __restrict__ xoutT, int write_f32) {
  __shared__ float sh2[128][22];   // [k(col)][r], 16 rows + pad (22 keeps 8B align)
  int r0 = blockIdx.x * 16, t = threadIdx.x;
  // 1) reduce partials + residual -> sh2 (transposed store)
#pragma unroll
  for (int q = 0; q < 2; q++) {
    int lin = t + q * 256;         // float4 index in 16x128 tile
    int r = lin >> 5, c = (lin & 31) * 4;
    size_t base4 = ((size_t)(r0 + r) * WOUT + c) >> 2;
    float4 s = {0.f, 0.f, 0.f, 0.f};
#pragma unroll
    for (int kc = 0; kc < KSPLIT; kc++) {
      float4 p = ((const float4*)P)[(size_t)kc * (NN * WOUT / 4) + base4];
      s.x += p.x; s.y += p.y; s.z += p.z; s.w += p.w;
    }
    float4 xv = ((const float4*)x0)[base4];
    s.x = 0.9f * s.x + 0.1f * xv.x;
    s.y = 0.9f * s.y + 0.1f * xv.y;
    s.z = 0.9f * s.z + 0.1f * xv.z;
    s.w = 0.9f * s.w + 0.1f * xv.w;
    sh2[c + 0][r] = s.x; sh2[c + 1][r] = s.y; sh2[c + 2][r] = s.z; sh2[c + 3][r] = s.w;
  }
  __syncthreads();
  // 2) dense h@Wl, register-tiled 2x4 (rows ty*2.., cols tx*4..)
  int tx = t & 31, ty = t >> 5;
  float2 hv[4];
#pragma unroll
  for (int j = 0; j < 4; j++) hv[j] = *(const float2*)&sh2[tx * 4 + j][ty * 2];
  float o[2][4] = {};
  for (int k = 0; k < WOUT; k++) {
    float2 a = *(const float2*)&sh2[k][ty * 2];
    float4 w = *(const float4*)&Wl[k * WOUT + tx * 4];
    o[0][0] += a.x * w.x; o[0][1] += a.x * w.y; o[0][2] += a.x * w.z; o[0][3] += a.x * w.w;
    o[1][0] += a.y * w.x; o[1][1] += a.y * w.y; o[1][2] += a.y * w.z; o[1][3] += a.y * w.w;
  }
  float c1 = 1.f - bl;
  float y[2][4];
  float hvv[2][4] = {{hv[0].x, hv[1].x, hv[2].x, hv[3].x},
                     {hv[0].y, hv[1].y, hv[2].y, hv[3].y}};
#pragma unroll
  for (int i = 0; i < 2; i++)
#pragma unroll
    for (int j = 0; j < 4; j++)
      y[i][j] = fmaxf(c1 * hvv[i][j] + bl * o[i][j], 0.f);
  if (write_f32) {
#pragma unroll
    for (int i = 0; i < 2; i++) {
      float4 v = {y[i][0], y[i][1], y[i][2], y[i][3]};
      *(float4*)&xout_f32[(size_t)(r0 + ty * 2 + i) * WOUT + tx * 4] = v;
    }
  }
  __syncthreads();   // done reading sh2 as h
#pragma unroll
  for (int i = 0; i < 2; i++)
#pragma unroll
    for (int j = 0; j < 4; j++)
      sh2[tx * 4 + j][ty * 2 + i] = y[i][j];
  __syncthreads();
  // 3) transposed bf16 write: col c, 8 rows per thread
  int c = t >> 1, half = t & 1;
  unsigned short tmp[8];
#pragma unroll
  for (int rr = 0; rr < 8; rr++) tmp[rr] = f2bf(sh2[c][half * 8 + rr]);
  *(ushort8_t*)&xoutT[(size_t)c * NN + r0 + half * 8] = *(ushort8_t*)&tmp[0];
}

// y = Z[tx]@W2 + b2 ; per-row log-softmax ; per-block loss partials
__global__ __launch_bounds__(256) void head_kernel(
    const float* __restrict__ Z, const int* __restrict__ txv, const int* __restrict__ tgt,
    const float* __restrict__ W2, const float* __restrict__ b2,
    float* __restrict__ out_y, float* __restrict__ lossp) {
  int tid = threadIdx.x;
  int mr = tid >> 4, c = tid & 15;
  int m = blockIdx.x * 16 + mr;
  const float* zr = Z + (size_t)txv[m] * WOUT;
  float acc = b2[c];
  for (int k = 0; k < WOUT; k++) acc += zr[k] * W2[k * NCLS + c];
  out_y[(size_t)m * NCLS + c] = acc;
  float mx = acc;
  for (int off = 8; off; off >>= 1) mx = fmaxf(mx, __shfl_xor(mx, off, 16));
  float ex = expf(acc - mx);
  float se = ex;
  for (int off = 8; off; off >>= 1) se += __shfl_xor(se, off, 16);
  float lse = mx + logf(se);
  float contrib = (c == tgt[m]) ? (lse - acc) : 0.f;
  __shared__ float red[256];
  red[tid] = contrib;
  __syncthreads();
  for (int stp = 128; stp; stp >>= 1) {
    if (tid < stp) red[tid] += red[tid + stp];
    __syncthreads();
  }
  if (tid == 0) lossp[blockIdx.x] = red[0];
}

__global__ void loss_final_kernel(const float* __restrict__ lossp, float* __restrict__ out_loss) {
  int lane = threadIdx.x;
  float v = (lane < 64) ? lossp[lane] : 0.f;
  for (int off = 32; off; off >>= 1) v += __shfl_down(v, off, 64);
  if (lane == 0) out_loss[0] = v / (float)MT;
}

// ---------------------------------------------------------------------------
extern "C" void kernel_launch(void* const* d_in, const int* in_sizes, int n_in,
                              void* d_out, int out_size, void* d_ws, size_t ws_size,
                              hipStream_t stream) {
  const float* A      = (const float*)d_in[0];
  const float* X      = (const float*)d_in[1];
  const int*   txv    = (const int*)d_in[2];
  const int*   tgt    = (const int*)d_in[3];
  const float* weight = (const float*)d_in[4];
  const float* attw   = (const float*)d_in[5];
  const float* attb   = (const float*)d_in[6];
  const float* attq   = (const float*)d_in[7];
  const float* Wg     = (const float*)d_in[8];
  const float* bg     = (const float*)d_in[9];
  const float* W0     = (const float*)d_in[10];
  const float* b0     = (const float*)d_in[11];
  const float* Wconvs = (const float*)d_in[12];
  const float* Wd1    = (const float*)d_in[13];
  const float* bd1    = (const float*)d_in[14];
  const float* W1     = (const float*)d_in[15];
  const float* b1     = (const float*)d_in[16];
  const float* W2     = (const float*)d_in[17];
  const float* b2     = (const float*)d_in[18];

  float* ws  = (float*)d_ws;
  int*   wsi = (int*)d_ws;

  // offsets in 4-byte units (~110 MB total; ws >= 1.3 GB per harness poison)
  const size_t O_GCNT  = 0;                         // 20480 ints
  const size_t O_BCNT  = 20480;                     // 4096
  const size_t O_FCNT  = 24576;                     // 20480
  const size_t O_DINV  = 45056;                     // 20480
  const size_t O_DIS   = 65536;                     // 4096
  const size_t O_TMPRE = 69632;                     // 640
  const size_t O_BETA  = 70272;                     // 16
  const size_t O_LOSSP = 70288;                     // 64
  const size_t O_GIDX  = 71680;                     // 1966080
  const size_t O_GVAL  = O_GIDX + 1966080;
  const size_t O_FIDX  = O_GVAL + 1966080;
  const size_t O_FVAL  = O_FIDX + 1966080;
  const size_t O_BIDX  = O_FVAL + 1966080;          // 1310720
  const size_t O_LGCN  = O_BIDX + 1310720;          // 2621440
  const size_t O_XW    = O_LGCN + 2621440;          // 524288
  const size_t O_X0    = O_XW   + 524288;           // 524288
  const size_t O_XA    = O_X0   + 524288;           // 524288
  const size_t O_XB    = O_XA   + 524288;           // 524288
  const size_t O_AB    = O_XB   + 524288;           // 8388608 (4096x4096 bf16)
  const size_t O_XBT0  = O_AB   + 8388608;          // 262144  (128x4096 bf16)
  const size_t O_XBT1  = O_XBT0 + 262144;           // 262144
  const size_t O_P     = O_XBT1 + 262144;           // 4194304 (8x4096x128 f32)
  // aliases (lifetimes verified by launch order):
  const size_t O_T1    = O_FVAL;   // [4096,512] dead before scan writes fval/bidx
  const size_t O_XCAT  = O_GIDX;   // [4096,1152] built after gidx/gval/fidx last reads

  hipMemsetAsync(ws + O_GCNT, 0, 45056 * 4, stream);   // gcnt+bcnt+fcnt
  hipMemsetAsync(ws + O_TMPRE, 0, 640 * 4, stream);

  dim3 blk(256);
  // Stage A: Xw = leaky(leaky(X@Wg+bg)@weight)
  gemm_kernel<<<dim3(WIN / 64, NN / 64), blk, 0, stream>>>(X, Wg, bg, ws + O_T1, NN, WIN, WIN, 2);
  gemm_kernel<<<dim3(WOUT / 64, NN / 64), blk, 0, stream>>>(ws + O_T1, weight, nullptr, ws + O_XW, NN, WIN, WOUT, 2);
  // Stage B: sparse structures + dense A_hat
  scan_rows_kernel<<<NN * 4, 256, 0, stream>>>(A, wsi + O_FCNT, wsi + O_FIDX, ws + O_FVAL,
                                               wsi + O_BCNT, wsi + O_BIDX);
  transpose_kernel<<<EE * NN, 64, 0, stream>>>(wsi + O_FCNT, wsi + O_FIDX, ws + O_FVAL,
                                               wsi + O_GCNT, wsi + O_GIDX, ws + O_GVAL);
  dinv_dis_kernel<<<80, 256, 0, stream>>>(wsi + O_GCNT, ws + O_GVAL, ws + O_DINV,
                                          wsi + O_BCNT, ws + O_DIS);
  build_ahat_kernel<<<NN, 256, 0, stream>>>(wsi + O_BCNT, wsi + O_BIDX, ws + O_DIS,
                                            (unsigned short*)(ws + O_AB));
  // Stage C: lgcn
  lgcn_kernel<<<dim3(NN, EE), 128, 0, stream>>>(wsi + O_GCNT, wsi + O_GIDX, ws + O_GVAL,
                                                ws + O_DINV, ws + O_XW, ws + O_LGCN);
  // Stage D: attention -> beta
  att_partial_kernel<<<dim3(32, EE), 128, 0, stream>>>(ws + O_LGCN, attw, ws + O_TMPRE);
  att_final_kernel<<<1, 64, 0, stream>>>(ws + O_TMPRE, attb, attq, ws + O_BETA);
  // Stage E: X_ and x0
  xcat_kernel<<<4096, 256, 0, stream>>>(ws + O_LGCN, X, ws + O_BETA, ws + O_XCAT);
  gemm_kernel<<<dim3(WOUT / 64, NN / 64), blk, 0, stream>>>(ws + O_XCAT, W0, b0, ws + O_X0, NN, HH0, WOUT, 1);
  xT_convert_kernel<<<NN / 32, 256, 0, stream>>>(ws + O_X0, (unsigned short*)(ws + O_XBT0));
  // Stage F: 64 GCNII layers (dense bf16 MFMA)
  for (int l = 0; l < NLAY; l++) {
    float bl = logf(0.5f / (float)(l + 1) + 1.0f);
    const unsigned short* xin = (const unsigned short*)(ws + ((l & 1) ? O_XBT1 : O_XBT0));
    unsigned short* xoT = (unsigned short*)(ws + ((l & 1) ? O_XBT0 : O_XBT1));
    spmm_kernel<<<64 * KSPLIT, 256, 0, stream>>>((const unsigned short*)(ws + O_AB), xin, ws + O_P);
    gcnii_epi_kernel<<<NN / 16, 256, 0, stream>>>(ws + O_P, ws + O_X0,
                                                  Wconvs + (size_t)l * WOUT * WOUT, bl,
                                                  ws + O_XA, xoT, (l == NLAY - 1) ? 1 : 0);
  }
  // Stage G: head (fp32 x in O_XA)
  gemm_kernel<<<dim3(WOUT / 64, NN / 64), blk, 0, stream>>>(ws + O_XA, Wd1, bd1, ws + O_XB, NN, WOUT, WOUT, 2);
  gemm_kernel<<<dim3(WOUT / 64, NN / 64), blk, 0, stream>>>(ws + O_XB, W1, b1, ws + O_X0, NN, WOUT, WOUT, 2);
  head_kernel<<<MT / 16, 256, 0, stream>>>(ws + O_X0, txv, tgt, W2, b2,
                                           (float*)d_out + 1, ws + O_LOSSP);
  loss_final_kernel<<<1, 64, 0, stream>>>(ws + O_LOSSP, (float*)d_out);
}

// Round 10
// 2365.704 us; speedup vs baseline: 2.9806x; 1.0097x over previous
//
#include <hip/hip_runtime.h>
#include <cstdint>
#include <cmath>

#define NN   4096
#define EE   5
#define WIN  512
#define WOUT 128
#define HH0  1152   // WIN + EE*WOUT
#define NLAY 64
#define NCLS 16
#define MT   1024
#define GCAP 96     // per-(e,node) list cap; Binomial(4096,0.01) max ~70
#define BCAP 320    // per-node union cap; Binomial(4096,0.049) max ~260
#define ECAP 48     // per-(e, quarter-row) cap
#define KSPLIT 8
#define KCHUNK 512  // KSPLIT*KCHUNK == NN
#define NTILE  8    // KCHUNK / 64

typedef __attribute__((ext_vector_type(8))) short     bf16x8_t;
typedef __attribute__((ext_vector_type(8))) unsigned short ushort8_t;
typedef __attribute__((ext_vector_type(4))) float     f32x4_t;

__device__ inline unsigned short f2bf(float f) {
  unsigned int u = __float_as_uint(f);
  unsigned int r = (u + 0x7FFFu + ((u >> 16) & 1u)) >> 16;  // RNE
  return (unsigned short)r;
}

// async global->LDS, 16B per lane: dest = lds_base(wave-uniform) + lane*16
__device__ __forceinline__ void gload16(const unsigned short* g, unsigned short* l) {
  __builtin_amdgcn_global_load_lds(
      (__attribute__((address_space(1))) void*)g,
      (__attribute__((address_space(3))) void*)l, 16, 0, 0);
}

// ---------------------------------------------------------------------------
// Generic register-tiled fp32 GEMM: C = act(A[M,K] @ W[K,N] + bias)
// 64x64 tile, 256 threads, 4x4 outputs/thread, BK=16. act:0=none,1=relu,2=leaky
// ---------------------------------------------------------------------------
__global__ __launch_bounds__(256) void gemm_kernel(
    const float* __restrict__ A, const float* __restrict__ W,
    const float* __restrict__ bias, float* __restrict__ C,
    int Mdim, int Kdim, int Ndim, int act) {
  __shared__ __align__(16) float sA[16][68];
  __shared__ __align__(16) float sW[16][64];
  int tid = threadIdx.x;
  int tx = tid & 15, ty = tid >> 4;
  int row0 = blockIdx.y * 64, col0 = blockIdx.x * 64;
  float acc[4][4] = {};
  int mA = tid >> 2;
  int kA = (tid & 3) << 2;
  int kW = tid >> 4;
  int nW = (tid & 15) << 2;
  for (int k0 = 0; k0 < Kdim; k0 += 16) {
    float4 av = *(const float4*)(A + (size_t)(row0 + mA) * Kdim + k0 + kA);
    float4 wv = *(const float4*)(W + (size_t)(k0 + kW) * Ndim + col0 + nW);
    sA[kA + 0][mA] = av.x;
    sA[kA + 1][mA] = av.y;
    sA[kA + 2][mA] = av.z;
    sA[kA + 3][mA] = av.w;
    *(float4*)&sW[kW][nW] = wv;
    __syncthreads();
#pragma unroll
    for (int kk = 0; kk < 16; kk++) {
      float4 a = *(const float4*)&sA[kk][ty << 2];
      float4 b = *(const float4*)&sW[kk][tx << 2];
      acc[0][0] += a.x * b.x; acc[0][1] += a.x * b.y; acc[0][2] += a.x * b.z; acc[0][3] += a.x * b.w;
      acc[1][0] += a.y * b.x; acc[1][1] += a.y * b.y; acc[1][2] += a.y * b.z; acc[1][3] += a.y * b.w;
      acc[2][0] += a.z * b.x; acc[2][1] += a.z * b.y; acc[2][2] += a.z * b.z; acc[2][3] += a.z * b.w;
      acc[3][0] += a.w * b.x; acc[3][1] += a.w * b.y; acc[3][2] += a.w * b.z; acc[3][3] += a.w * b.w;
    }
    __syncthreads();
  }
#pragma unroll
  for (int i = 0; i < 4; i++) {
    int r = row0 + (ty << 2) + i;
#pragma unroll
    for (int jc = 0; jc < 4; jc++) {
      int c = col0 + (tx << 2) + jc;
      float o = acc[i][jc];
      if (bias) o += bias[c];
      if (act == 1) o = fmaxf(o, 0.f);
      else if (act == 2) o = (o >= 0.f) ? o : 0.01f * o;
      C[(size_t)r * Ndim + c] = o;
    }
  }
}

// ---------------------------------------------------------------------------
// Narrow-N fp32 GEMM: 32x64 tile, 256 threads, 2x4 outputs/thread, BK=16.
// For N=128 shapes the 64x64 kernel launches only 128 blocks (half chip);
// this gives grid (N/64, M/32) = 256 blocks. Per-output accumulation order
// (ascending k) identical to gemm_kernel -> bit-identical fp32 results.
// ---------------------------------------------------------------------------
__global__ __launch_bounds__(256) void gemm32_kernel(
    const float* __restrict__ A, const float* __restrict__ W,
    const float* __restrict__ bias, float* __restrict__ C,
    int Mdim, int Kdim, int Ndim, int act) {
  __shared__ __align__(16) float sA[16][36];   // [k][m], 32 rows + pad
  __shared__ __align__(16) float sW[16][64];
  int tid = threadIdx.x;
  int tx = tid & 15, ty = tid >> 4;            // ty 0..15 -> rows ty*2..+1
  int row0 = blockIdx.y * 32, col0 = blockIdx.x * 64;
  float acc[2][4] = {};
  int mA = tid >> 3;                            // 0..31
  int kA = (tid & 7) << 1;                      // 0,2,..,14
  int kW = tid >> 4;
  int nW = (tid & 15) << 2;
  for (int k0 = 0; k0 < Kdim; k0 += 16) {
    float2 av = *(const float2*)(A + (size_t)(row0 + mA) * Kdim + k0 + kA);
    float4 wv = *(const float4*)(W + (size_t)(k0 + kW) * Ndim + col0 + nW);
    sA[kA + 0][mA] = av.x;
    sA[kA + 1][mA] = av.y;
    *(float4*)&sW[kW][nW] = wv;
    __syncthreads();
#pragma unroll
    for (int kk = 0; kk < 16; kk++) {
      float2 a = *(const float2*)&sA[kk][ty << 1];
      float4 b = *(const float4*)&sW[kk][tx << 2];
      acc[0][0] += a.x * b.x; acc[0][1] += a.x * b.y; acc[0][2] += a.x * b.z; acc[0][3] += a.x * b.w;
      acc[1][0] += a.y * b.x; acc[1][1] += a.y * b.y; acc[1][2] += a.y * b.z; acc[1][3] += a.y * b.w;
    }
    __syncthreads();
  }
#pragma unroll
  for (int i = 0; i < 2; i++) {
    int r = row0 + (ty << 1) + i;
#pragma unroll
    for (int jc = 0; jc < 4; jc++) {
      int c = col0 + (tx << 2) + jc;
      float o = acc[i][jc];
      if (bias) o += bias[c];
      if (act == 1) o = fmaxf(o, 0.f);
      else if (act == 2) o = (o >= 0.f) ? o : 0.01f * o;
      C[(size_t)r * Ndim + c] = o;
    }
  }
}

// ---------------------------------------------------------------------------
// Forward scan: block = quarter-row, coalesced list build.
// ---------------------------------------------------------------------------
__global__ __launch_bounds__(256) void scan_rows_kernel(
    const float* __restrict__ A, int* __restrict__ fcnt, int* __restrict__ fidx,
    float* __restrict__ fval, int* __restrict__ bcnt, int* __restrict__ bidx) {
  __shared__ int   lbuf[1024];
  __shared__ int   lcnt;
  __shared__ int   ecnt[EE];
  __shared__ int   en2[EE][ECAP];
  __shared__ float ev[EE][ECAP];
  __shared__ int   rbase;
  __shared__ int   gbase[EE];
  int tid = threadIdx.x;
  int n1 = blockIdx.x >> 2;
  int qb = (blockIdx.x & 3) << 10;
  if (tid == 0) lcnt = 0;
  if (tid < EE) ecnt[tid] = 0;
  __syncthreads();
  const float4* src = (const float4*)(A + ((size_t)n1 * NN + qb) * EE);
  float buf[20];
  float4* bf4 = (float4*)buf;
#pragma unroll
  for (int c = 0; c < 5; c++) bf4[c] = src[tid * 5 + c];
  int n2base = qb + tid * 4;
#pragma unroll
  for (int u = 0; u < 4; u++) {
    int n2 = n2base + u;
    if (n2 == n1) continue;
    bool any = false;
#pragma unroll
    for (int e = 0; e < EE; e++) {
      float v = buf[u * 5 + e];
      if (v != 0.f) {
        any = true;
        int s = atomicAdd(&ecnt[e], 1);
        if (s < ECAP) { en2[e][s] = n2; ev[e][s] = v; }
      }
    }
    if (any) {
      int s = atomicAdd(&lcnt, 1);
      lbuf[s] = n2;
    }
  }
  __syncthreads();
  if (tid == 0) rbase = atomicAdd(&bcnt[n1], lcnt);
  if (tid < EE) gbase[tid] = atomicAdd(&fcnt[tid * NN + n1], min(ecnt[tid], ECAP));
  __syncthreads();
  int c = lcnt, rb = rbase;
  for (int s = tid; s < c; s += 256)
    if (rb + s < BCAP) bidx[(size_t)n1 * BCAP + rb + s] = lbuf[s];
#pragma unroll
  for (int e = 0; e < EE; e++) {
    int ec = min(ecnt[e], ECAP), gb = gbase[e];
    size_t base = ((size_t)e * NN + n1) * GCAP;
    for (int s = tid; s < ec; s += 256) {
      if (gb + s < GCAP) {
        fidx[base + gb + s] = en2[e][s];
        fval[base + gb + s] = ev[e][s];
      }
    }
  }
}

// Forward -> transposed gcn lists (for lgcn).
__global__ __launch_bounds__(64) void transpose_kernel(
    const int* __restrict__ fcnt, const int* __restrict__ fidx, const float* __restrict__ fval,
    int* __restrict__ gcnt, int* __restrict__ gidx, float* __restrict__ gval) {
  int id = blockIdx.x;                      // e*NN + n1
  int n1 = id & (NN - 1);
  int e  = id >> 12;
  int c = min(fcnt[id], GCAP);
  for (int s = threadIdx.x; s < c; s += 64) {
    int   n2 = fidx[(size_t)id * GCAP + s];
    float v  = fval[(size_t)id * GCAP + s];
    int t = e * NN + n2;
    int slot = atomicAdd(&gcnt[t], 1);
    if (slot < GCAP) {
      gidx[(size_t)t * GCAP + slot] = n1;
      gval[(size_t)t * GCAP + slot] = v;
    }
  }
}

// dinv[e,i] = 1/(1 + sum gval)   ;   dis[i] = rsqrt(1 + bcnt[i])
__global__ void dinv_dis_kernel(const int* __restrict__ gcnt, const float* __restrict__ gval,
                                float* __restrict__ dinv, const int* __restrict__ bcnt,
                                float* __restrict__ dis) {
  int t = blockIdx.x * 256 + threadIdx.x;
  if (t < EE * NN) {
    int cnt = min(gcnt[t], GCAP);
    float s = 1.0f;
    for (int k = 0; k < cnt; k++) s += gval[(size_t)t * GCAP + k];
    dinv[t] = 1.0f / s;
  }
  if (t < NN) dis[t] = rsqrtf(1.0f + (float)min(bcnt[t], BCAP));
}

// ---------------------------------------------------------------------------
// Dense A_hat bf16 build: one block per row i; bitmap of neighbors in LDS,
// coalesced 8 KB row write. Ab[i][j] = (B[i][j]||i==j) ? dis[i]*dis[j] : 0.
// ---------------------------------------------------------------------------
__global__ __launch_bounds__(256) void build_ahat_kernel(
    const int* __restrict__ bcnt, const int* __restrict__ bidx,
    const float* __restrict__ dis, unsigned short* __restrict__ Ab) {
  __shared__ unsigned int bits[128];
  int i = blockIdx.x, t = threadIdx.x;
  if (t < 128) bits[t] = 0;
  __syncthreads();
  int cnt = min(bcnt[i], BCAP);
  for (int s = t; s < cnt; s += 256) {
    int j = bidx[(size_t)i * BCAP + s];
    atomicOr(&bits[j >> 5], 1u << (j & 31));
  }
  __syncthreads();
  float di = dis[i];
  int c0 = t * 16;
  unsigned short out[16];
#pragma unroll
  for (int u = 0; u < 16; u++) {
    int j = c0 + u;
    bool on = ((bits[j >> 5] >> (j & 31)) & 1u) || (j == i);
    out[u] = on ? f2bf(di * dis[j]) : (unsigned short)0;
  }
  *(ushort8_t*)&Ab[(size_t)i * NN + c0]     = *(ushort8_t*)&out[0];
  *(ushort8_t*)&Ab[(size_t)i * NN + c0 + 8] = *(ushort8_t*)&out[8];
}

// lgcn[e,i,d] = relu( dinv[e,i] * (Xw[i,d] + sum_s v_s * Xw[j_s,d]) )
__global__ __launch_bounds__(128) void lgcn_kernel(
    const int* __restrict__ gcnt, const int* __restrict__ gidx, const float* __restrict__ gval,
    const float* __restrict__ dinv, const float* __restrict__ Xw, float* __restrict__ lgcn) {
  int i = blockIdx.x, e = blockIdx.y, d = threadIdx.x;
  int t = e * NN + i;
  int cnt = min(gcnt[t], GCAP);
  __shared__ int   sj[GCAP];
  __shared__ float sv[GCAP];
  for (int s = d; s < cnt; s += 128) {
    sj[s] = gidx[(size_t)t * GCAP + s];
    sv[s] = gval[(size_t)t * GCAP + s];
  }
  __syncthreads();
  float acc = Xw[(size_t)i * WOUT + d];
  for (int s = 0; s < cnt; s++) acc += sv[s] * Xw[(size_t)sj[s] * WOUT + d];
  float r = dinv[t] * acc;
  lgcn[(size_t)t * WOUT + d] = fmaxf(r, 0.f);
}

__global__ void att_partial_kernel(const float* __restrict__ lgcn, const float* __restrict__ attw,
                                   float* __restrict__ tm_pre) {
  int e = blockIdx.y, d = threadIdx.x;
  int nbase = blockIdx.x * 128;
  float acc = 0.f;
  for (int k = 0; k < 128; k++) {
    int n = nbase + k;
    acc += attw[n] * lgcn[((size_t)(e * NN + n)) * WOUT + d];
  }
  atomicAdd(&tm_pre[e * WOUT + d], acc);
}

__global__ void att_final_kernel(const float* __restrict__ tm_pre, const float* __restrict__ attb,
                                 const float* __restrict__ attq, float* __restrict__ beta) {
  int lane = threadIdx.x;  // 64
  __shared__ float sw[EE];
  for (int e = 0; e < EE; e++) {
    float v = 0.f;
    for (int d = lane; d < WOUT; d += 64) {
      float tmv = tanhf(tm_pre[e * WOUT + d] + attb[d]);
      v += tmv * attq[d];
    }
    for (int off = 32; off; off >>= 1) v += __shfl_down(v, off, 64);
    if (lane == 0) sw[e] = v;
  }
  __syncthreads();
  if (lane == 0) {
    float mx = sw[0];
    for (int e = 1; e < EE; e++) mx = fmaxf(mx, sw[e]);
    float se = 0.f, ex[EE];
    for (int e = 0; e < EE; e++) { ex[e] = expf(sw[e] - mx); se += ex[e]; }
    for (int e = 0; e < EE; e++) beta[e] = ex[e] / se * (float)EE;
  }
}

__global__ void xcat_kernel(const float* __restrict__ lgcn, const float* __restrict__ X,
                            const float* __restrict__ beta, float* __restrict__ Xc) {
  int idx = blockIdx.x * 256 + threadIdx.x;
  const int total = NN * HH0;
  for (; idx < total; idx += gridDim.x * 256) {
    int n = idx / HH0, c = idx - n * HH0;
    float v;
    if (c < EE * WOUT) {
      int e = c >> 7, d = c & 127;
      v = beta[e] * lgcn[((size_t)(e * NN + n)) * WOUT + d];
    } else {
      v = X[(size_t)n * WIN + (c - EE * WOUT)];
    }
    Xc[idx] = v;
  }
}

// ---------------------------------------------------------------------------
// x (fp32 [NN][128]) -> xT (bf16 [128][NN]) via LDS transpose. 32 rows/block.
// ---------------------------------------------------------------------------
__global__ __launch_bounds__(256) void xT_convert_kernel(
    const float* __restrict__ x, unsigned short* __restrict__ xT) {
  __shared__ float sh2[128][36];    // [c][r]
  int r0 = blockIdx.x * 32, t = threadIdx.x;
  const float4* x4 = (const float4*)(x + (size_t)r0 * WOUT);
#pragma unroll
  for (int q = 0; q < 4; q++) {
    int lin = t + q * 256;          // float4 index in 32x128 tile
    int r = lin >> 5, c = (lin & 31) * 4;
    float4 v = x4[lin];
    sh2[c + 0][r] = v.x; sh2[c + 1][r] = v.y; sh2[c + 2][r] = v.z; sh2[c + 3][r] = v.w;
  }
  __syncthreads();
  int c = t >> 1, half = t & 1;
  unsigned short tmp[16];
#pragma unroll
  for (int rr = 0; rr < 16; rr++) tmp[rr] = f2bf(sh2[c][half * 16 + rr]);
  *(ushort8_t*)&xT[(size_t)c * NN + r0 + half * 16]     = *(ushort8_t*)&tmp[0];
  *(ushort8_t*)&xT[(size_t)c * NN + r0 + half * 16 + 8] = *(ushort8_t*)&tmp[8];
}

// ---------------------------------------------------------------------------
// SpMM-as-dense-GEMM, bf16 MFMA 16x16x32. Block: 64 rows x 128 cols,
// K-chunk 512 (split-K 8). Grid 64x8=512 blocks (2/CU). 4 waves, each a
// 32x64 sub-tile (2x4 MFMA tiles). Double-buffered BK=64 stages (two BK=32
// sub-tiles, 64B rows -> contiguous conflict-free ds_read_b128),
// global_load_lds width=16 staging via 6 precomputed chunk descriptors per
// wave (24 x 1KB chunks per tile).
// LDS per buffer: A[2][64][32] (8KB) then X[2][128][32] (16KB) = 12288 shorts.
// Layouts (m89/m91-verified): A-frag A[m=lane&15][k=quad*8+j];
// B-frag B[k=quad*8+j][n=lane&15]; C/D col=lane&15,row=quad*4+reg.
// ---------------------------------------------------------------------------
__global__ __launch_bounds__(256) void spmm_kernel(
    const unsigned short* __restrict__ Ab, const unsigned short* __restrict__ xbT,
    float* __restrict__ P) {
  __shared__ __align__(16) unsigned short sT[2][12288];
  int t = threadIdx.x;
  int rt = blockIdx.x & 63, kc = blockIdx.x >> 6;
  int r0 = rt * 64, k0 = kc * KCHUNK;
  int wave = t >> 6, lane = t & 63;
  int wr = (wave & 1) * 32, wc = (wave >> 1) * 64;
  int quad = lane >> 4, mrow = lane & 15;
  f32x4_t acc[2][4] = {};

  // 6 staging chunks per wave; chunk = 16 rows x 64B. c<8: A, else X.
  const unsigned short* gq[6];
  int lq[6];
#pragma unroll
  for (int q = 0; q < 6; q++) {
    int c = wave * 6 + q;
    if (c < 8) {
      int sub = c >> 2, rb = c & 3;
      gq[q] = Ab + (size_t)(r0 + rb * 16 + (lane >> 2)) * NN + k0 + sub * 32 + (lane & 3) * 8;
      lq[q] = sub * 2048 + rb * 512;
    } else {
      int cc = c - 8;
      int sub = cc >> 3, rb = cc & 7;
      gq[q] = xbT + (size_t)(rb * 16 + (lane >> 2)) * NN + k0 + sub * 32 + (lane & 3) * 8;
      lq[q] = 4096 + sub * 4096 + rb * 512;
    }
  }

#define STAGE(BUF, TS)                                         \
  {                                                            \
    unsigned short* lb = &sT[(BUF)][0];                        \
    _Pragma("unroll")                                          \
    for (int q = 0; q < 6; q++)                                \
      gload16(gq[q] + (TS) * 64, lb + lq[q]);                  \
  }

  STAGE(0, 0);
  asm volatile("s_waitcnt vmcnt(0)" ::: "memory");
  __builtin_amdgcn_s_barrier();

  int cur = 0;
  for (int tt = 0; tt < NTILE; tt++) {
    if (tt < NTILE - 1) STAGE(cur ^ 1, tt + 1);
    const unsigned short* base = &sT[cur][0];
    bf16x8_t af[2][2], bfv[2][4];
#pragma unroll
    for (int kk = 0; kk < 2; kk++) {
#pragma unroll
      for (int mi = 0; mi < 2; mi++)
        af[kk][mi] = *(const bf16x8_t*)&base[kk * 2048 + (wr + mi * 16 + mrow) * 32 + quad * 8];
#pragma unroll
      for (int nj = 0; nj < 4; nj++)
        bfv[kk][nj] = *(const bf16x8_t*)&base[4096 + kk * 4096 + (wc + nj * 16 + mrow) * 32 + quad * 8];
    }
#pragma unroll
    for (int kk = 0; kk < 2; kk++)
#pragma unroll
      for (int mi = 0; mi < 2; mi++)
#pragma unroll
        for (int nj = 0; nj < 4; nj++)
          acc[mi][nj] = __builtin_amdgcn_mfma_f32_16x16x32_bf16(af[kk][mi], bfv[kk][nj], acc[mi][nj], 0, 0, 0);
    if (tt < NTILE - 1) {
      asm volatile("s_waitcnt vmcnt(0)" ::: "memory");  // next-tile loads landed
      __builtin_amdgcn_s_barrier();                      // reads done, writes visible
      cur ^= 1;
    }
  }
#undef STAGE

  float* Pk = P + (size_t)kc * (NN * WOUT);
#pragma unroll
  for (int mi = 0; mi < 2; mi++)
#pragma unroll
    for (int nj = 0; nj < 4; nj++) {
#pragma unroll
      for (int r4 = 0; r4 < 4; r4++) {
        int row = r0 + wr + mi * 16 + quad * 4 + r4;
        int col = wc + nj * 16 + mrow;
        Pk[(size_t)row * WOUT + col] = acc[mi][nj][r4];
      }
    }
}

// ---------------------------------------------------------------------------
// GCNII epilogue: h = sum_kc P + residual; y = relu((1-bl)h + bl*h@Wl);
// writes xT bf16 (always) and x fp32 (last layer).
// 16 rows/block -> 256 blocks (full chip), 256 thr, 2x4 outputs/thread.
// ---------------------------------------------------------------------------
__global__ __launch_bounds__(256) void gcnii_epi_kernel(
    const float* __restrict__ P, const float* __restrict__ x0,
    const float* __restrict__ Wl, float bl,
    float* __restrict__ xout_f32, unsigned short* __restrict__ xoutT, int write_f32) {
  __shared__ float sh2[128][22];   // [k(col)][r], 16 rows + pad (22 keeps 8B align)
  int r0 = blockIdx.x * 16, t = threadIdx.x;
  // 1) reduce partials + residual -> sh2 (transposed store)
#pragma unroll
  for (int q = 0; q < 2; q++) {
    int lin = t + q * 256;         // float4 index in 16x128 tile
    int r = lin >> 5, c = (lin & 31) * 4;
    size_t base4 = ((size_t)(r0 + r) * WOUT + c) >> 2;
    float4 s = {0.f, 0.f, 0.f, 0.f};
#pragma unroll
    for (int kc = 0; kc < KSPLIT; kc++) {
      float4 p = ((const float4*)P)[(size_t)kc * (NN * WOUT / 4) + base4];
      s.x += p.x; s.y += p.y; s.z += p.z; s.w += p.w;
    }
    float4 xv = ((const float4*)x0)[base4];
    s.x = 0.9f * s.x + 0.1f * xv.x;
    s.y = 0.9f * s.y + 0.1f * xv.y;
    s.z = 0.9f * s.z + 0.1f * xv.z;
    s.w = 0.9f * s.w + 0.1f * xv.w;
    sh2[c + 0][r] = s.x; sh2[c + 1][r] = s.y; sh2[c + 2][r] = s.z; sh2[c + 3][r] = s.w;
  }
  __syncthreads();
  // 2) dense h@Wl, register-tiled 2x4 (rows ty*2.., cols tx*4..)
  int tx = t & 31, ty = t >> 5;
  float2 hv[4];
#pragma unroll
  for (int j = 0; j < 4; j++) hv[j] = *(const float2*)&sh2[tx * 4 + j][ty * 2];
  float o[2][4] = {};
  for (int k = 0; k < WOUT; k++) {
    float2 a = *(const float2*)&sh2[k][ty * 2];
    float4 w = *(const float4*)&Wl[k * WOUT + tx * 4];
    o[0][0] += a.x * w.x; o[0][1] += a.x * w.y; o[0][2] += a.x * w.z; o[0][3] += a.x * w.w;
    o[1][0] += a.y * w.x; o[1][1] += a.y * w.y; o[1][2] += a.y * w.z; o[1][3] += a.y * w.w;
  }
  float c1 = 1.f - bl;
  float y[2][4];
  float hvv[2][4] = {{hv[0].x, hv[1].x, hv[2].x, hv[3].x},
                     {hv[0].y, hv[1].y, hv[2].y, hv[3].y}};
#pragma unroll
  for (int i = 0; i < 2; i++)
#pragma unroll
    for (int j = 0; j < 4; j++)
      y[i][j] = fmaxf(c1 * hvv[i][j] + bl * o[i][j], 0.f);
  if (write_f32) {
#pragma unroll
    for (int i = 0; i < 2; i++) {
      float4 v = {y[i][0], y[i][1], y[i][2], y[i][3]};
      *(float4*)&xout_f32[(size_t)(r0 + ty * 2 + i) * WOUT + tx * 4] = v;
    }
  }
  __syncthreads();   // done reading sh2 as h
#pragma unroll
  for (int i = 0; i < 2; i++)
#pragma unroll
    for (int j = 0; j < 4; j++)
      sh2[tx * 4 + j][ty * 2 + i] = y[i][j];
  __syncthreads();
  // 3) transposed bf16 write: col c, 8 rows per thread
  int c = t >> 1, half = t & 1;
  unsigned short tmp[8];
#pragma unroll
  for (int rr = 0; rr < 8; rr++) tmp[rr] = f2bf(sh2[c][half * 8 + rr]);
  *(ushort8_t*)&xoutT[(size_t)c * NN + r0 + half * 8] = *(ushort8_t*)&tmp[0];
}

// y = Z[tx]@W2 + b2 ; per-row log-softmax ; per-block loss partials
__global__ __launch_bounds__(256) void head_kernel(
    const float* __restrict__ Z, const int* __restrict__ txv, const int* __restrict__ tgt,
    const float* __restrict__ W2, const float* __restrict__ b2,
    float* __restrict__ out_y, float* __restrict__ lossp) {
  int tid = threadIdx.x;
  int mr = tid >> 4, c = tid & 15;
  int m = blockIdx.x * 16 + mr;
  const float* zr = Z + (size_t)txv[m] * WOUT;
  float acc = b2[c];
  for (int k = 0; k < WOUT; k++) acc += zr[k] * W2[k * NCLS + c];
  out_y[(size_t)m * NCLS + c] = acc;
  float mx = acc;
  for (int off = 8; off; off >>= 1) mx = fmaxf(mx, __shfl_xor(mx, off, 16));
  float ex = expf(acc - mx);
  float se = ex;
  for (int off = 8; off; off >>= 1) se += __shfl_xor(se, off, 16);
  float lse = mx + logf(se);
  float contrib = (c == tgt[m]) ? (lse - acc) : 0.f;
  __shared__ float red[256];
  red[tid] = contrib;
  __syncthreads();
  for (int stp = 128; stp; stp >>= 1) {
    if (tid < stp) red[tid] += red[tid + stp];
    __syncthreads();
  }
  if (tid == 0) lossp[blockIdx.x] = red[0];
}

__global__ void loss_final_kernel(const float* __restrict__ lossp, float* __restrict__ out_loss) {
  int lane = threadIdx.x;
  float v = (lane < 64) ? lossp[lane] : 0.f;
  for (int off = 32; off; off >>= 1) v += __shfl_down(v, off, 64);
  if (lane == 0) out_loss[0] = v / (float)MT;
}

// ---------------------------------------------------------------------------
extern "C" void kernel_launch(void* const* d_in, const int* in_sizes, int n_in,
                              void* d_out, int out_size, void* d_ws, size_t ws_size,
                              hipStream_t stream) {
  const float* A      = (const float*)d_in[0];
  const float* X      = (const float*)d_in[1];
  const int*   txv    = (const int*)d_in[2];
  const int*   tgt    = (const int*)d_in[3];
  const float* weight = (const float*)d_in[4];
  const float* attw   = (const float*)d_in[5];
  const float* attb   = (const float*)d_in[6];
  const float* attq   = (const float*)d_in[7];
  const float* Wg     = (const float*)d_in[8];
  const float* bg     = (const float*)d_in[9];
  const float* W0     = (const float*)d_in[10];
  const float* b0     = (const float*)d_in[11];
  const float* Wconvs = (const float*)d_in[12];
  const float* Wd1    = (const float*)d_in[13];
  const float* bd1    = (const float*)d_in[14];
  const float* W1     = (const float*)d_in[15];
  const float* b1     = (const float*)d_in[16];
  const float* W2     = (const float*)d_in[17];
  const float* b2     = (const float*)d_in[18];

  float* ws  = (float*)d_ws;
  int*   wsi = (int*)d_ws;

  // offsets in 4-byte units (~110 MB total; ws >= 1.3 GB per harness poison)
  const size_t O_GCNT  = 0;                         // 20480 ints
  const size_t O_BCNT  = 20480;                     // 4096
  const size_t O_FCNT  = 24576;                     // 20480
  const size_t O_DINV  = 45056;                     // 20480
  const size_t O_DIS   = 65536;                     // 4096
  const size_t O_TMPRE = 69632;                     // 640
  const size_t O_BETA  = 70272;                     // 16
  const size_t O_LOSSP = 70288;                     // 64
  const size_t O_GIDX  = 71680;                     // 1966080
  const size_t O_GVAL  = O_GIDX + 1966080;
  const size_t O_FIDX  = O_GVAL + 1966080;
  const size_t O_FVAL  = O_FIDX + 1966080;
  const size_t O_BIDX  = O_FVAL + 1966080;          // 1310720
  const size_t O_LGCN  = O_BIDX + 1310720;          // 2621440
  const size_t O_XW    = O_LGCN + 2621440;          // 524288
  const size_t O_X0    = O_XW   + 524288;           // 524288
  const size_t O_XA    = O_X0   + 524288;           // 524288
  const size_t O_XB    = O_XA   + 524288;           // 524288
  const size_t O_AB    = O_XB   + 524288;           // 8388608 (4096x4096 bf16)
  const size_t O_XBT0  = O_AB   + 8388608;          // 262144  (128x4096 bf16)
  const size_t O_XBT1  = O_XBT0 + 262144;           // 262144
  const size_t O_P     = O_XBT1 + 262144;           // 4194304 (8x4096x128 f32)
  // aliases (lifetimes verified by launch order):
  const size_t O_T1    = O_FVAL;   // [4096,512] dead before scan writes fval/bidx
  const size_t O_XCAT  = O_GIDX;   // [4096,1152] built after gidx/gval/fidx last reads

  hipMemsetAsync(ws + O_GCNT, 0, 45056 * 4, stream);   // gcnt+bcnt+fcnt
  hipMemsetAsync(ws + O_TMPRE, 0, 640 * 4, stream);

  dim3 blk(256);
  // Stage A: Xw = leaky(leaky(X@Wg+bg)@weight)
  gemm_kernel<<<dim3(WIN / 64, NN / 64), blk, 0, stream>>>(X, Wg, bg, ws + O_T1, NN, WIN, WIN, 2);
  gemm32_kernel<<<dim3(WOUT / 64, NN / 32), blk, 0, stream>>>(ws + O_T1, weight, nullptr, ws + O_XW, NN, WIN, WOUT, 2);
  // Stage B: sparse structures + dense A_hat
  scan_rows_kernel<<<NN * 4, 256, 0, stream>>>(A, wsi + O_FCNT, wsi + O_FIDX, ws + O_FVAL,
                                               wsi + O_BCNT, wsi + O_BIDX);
  transpose_kernel<<<EE * NN, 64, 0, stream>>>(wsi + O_FCNT, wsi + O_FIDX, ws + O_FVAL,
                                               wsi + O_GCNT, wsi + O_GIDX, ws + O_GVAL);
  dinv_dis_kernel<<<80, 256, 0, stream>>>(wsi + O_GCNT, ws + O_GVAL, ws + O_DINV,
                                          wsi + O_BCNT, ws + O_DIS);
  build_ahat_kernel<<<NN, 256, 0, stream>>>(wsi + O_BCNT, wsi + O_BIDX, ws + O_DIS,
                                            (unsigned short*)(ws + O_AB));
  // Stage C: lgcn
  lgcn_kernel<<<dim3(NN, EE), 128, 0, stream>>>(wsi + O_GCNT, wsi + O_GIDX, ws + O_GVAL,
                                                ws + O_DINV, ws + O_XW, ws + O_LGCN);
  // Stage D: attention -> beta
  att_partial_kernel<<<dim3(32, EE), 128, 0, stream>>>(ws + O_LGCN, attw, ws + O_TMPRE);
  att_final_kernel<<<1, 64, 0, stream>>>(ws + O_TMPRE, attb, attq, ws + O_BETA);
  // Stage E: X_ and x0
  xcat_kernel<<<4096, 256, 0, stream>>>(ws + O_LGCN, X, ws + O_BETA, ws + O_XCAT);
  gemm32_kernel<<<dim3(WOUT / 64, NN / 32), blk, 0, stream>>>(ws + O_XCAT, W0, b0, ws + O_X0, NN, HH0, WOUT, 1);
  xT_convert_kernel<<<NN / 32, 256, 0, stream>>>(ws + O_X0, (unsigned short*)(ws + O_XBT0));
  // Stage F: 64 GCNII layers (dense bf16 MFMA)
  for (int l = 0; l < NLAY; l++) {
    float bl = logf(0.5f / (float)(l + 1) + 1.0f);
    const unsigned short* xin = (const unsigned short*)(ws + ((l & 1) ? O_XBT1 : O_XBT0));
    unsigned short* xoT = (unsigned short*)(ws + ((l & 1) ? O_XBT0 : O_XBT1));
    spmm_kernel<<<64 * KSPLIT, 256, 0, stream>>>((const unsigned short*)(ws + O_AB), xin, ws + O_P);
    gcnii_epi_kernel<<<NN / 16, 256, 0, stream>>>(ws + O_P, ws + O_X0,
                                                  Wconvs + (size_t)l * WOUT * WOUT, bl,
                                                  ws + O_XA, xoT, (l == NLAY - 1) ? 1 : 0);
  }
  // Stage G: head (fp32 x in O_XA)
  gemm32_kernel<<<dim3(WOUT / 64, NN / 32), blk, 0, stream>>>(ws + O_XA, Wd1, bd1, ws + O_XB, NN, WOUT, WOUT, 2);
  gemm32_kernel<<<dim3(WOUT / 64, NN / 32), blk, 0, stream>>>(ws + O_XB, W1, b1, ws + O_X0, NN, WOUT, WOUT, 2);
  head_kernel<<<MT / 16, 256, 0, stream>>>(ws + O_X0, txv, tgt, W2, b2,
                                           (float*)d_out + 1, ws + O_LOSSP);
  loss_final_kernel<<<1, 64, 0, stream>>>(ws + O_LOSSP, (float*)d_out);
}